// Round 5
// baseline (189.696 us; speedup 1.0000x reference)
//
#include <hip/hip_runtime.h>
#include <hip/hip_bf16.h>

#define B_   4
#define C_   256
#define CO_  256
#define H_   64
#define W_   64
#define HW_  4096

typedef __attribute__((ext_vector_type(8))) short short8;
typedef __attribute__((ext_vector_type(4))) float f32x4;

static __device__ __forceinline__ unsigned short f2bf(float f) {
    unsigned u = __builtin_bit_cast(unsigned, f);
    unsigned r = (u + 0x7fffu + ((u >> 16) & 1u)) >> 16;
    return (unsigned short)r;
}
static __device__ __forceinline__ float bf2f(unsigned short s) {
    unsigned u = ((unsigned)s) << 16;
    return __builtin_bit_cast(float, u);
}

// ---------------- K1: NCHW f32 -> NHWC bf16 transpose (32hw x 128c tiles) ------------
__global__ void k_transpose(const float* __restrict__ x, unsigned short* __restrict__ xT)
{
    __shared__ float t[32][136];
    int bid = blockIdx.x;            // 1024 = b(4) * hwT(128) * cT(2)
    int b   = bid >> 8;
    int rem = bid & 255;
    int hwT = rem >> 1, cT = rem & 1;
    int hw0 = hwT * 32, c0 = cT * 128;
    int tid = threadIdx.x;
    const float* src = x + (size_t)b * C_ * HW_;
    {
        int hwi = tid & 31, cr = tid >> 5;
#pragma unroll
        for (int ps = 0; ps < 16; ++ps) {
            int c = cr + ps * 8;
            t[hwi][c] = src[(size_t)(c0 + c) * HW_ + hw0 + hwi];
        }
    }
    __syncthreads();
    {
        int c4 = (tid & 31) * 4, hwr = tid >> 5;
        unsigned short* dst = xT + (size_t)(((b << 12) + hw0) * 256) + c0 + c4;
#pragma unroll
        for (int ps = 0; ps < 4; ++ps) {
            int hw = hwr + ps * 8;
            f32x4 v = *(const f32x4*)&t[hw][c4];
            ushort4 u;
            u.x = f2bf(v.x); u.y = f2bf(v.y); u.z = f2bf(v.z); u.w = f2bf(v.w);
            *(ushort4*)(dst + (size_t)hw * 256) = u;
        }
    }
}

// ---------------- K2: offsets — 8 positions per block, LDS window (R3 version) -------
__global__ void k_offsets(const unsigned short* __restrict__ xT,
                          const float* __restrict__ dwc_w,
                          const float* __restrict__ ln_w,
                          const float* __restrict__ ln_b,
                          const float* __restrict__ fcd_w,
                          const float* __restrict__ fca_w,
                          float* __restrict__ OX, float* __restrict__ OY)
{
    __shared__ unsigned short win[30][256];   // [r*10+xc][ch]
    __shared__ float red[2][4][16];           // [parity][s1,s2,d1,d2][wave]
    int bi = blockIdx.x;
    int oct = ((bi & 7) << 8) | (bi >> 3);    // XCD swizzle
    int b = oct >> 9, rem = oct & 511, y = rem >> 3, xo = (rem & 7) << 3;
    int c = threadIdx.x;

    for (int i = 0; i < 30; ++i) {
        int r = i / 10, xc = i - r * 10;
        int gy = y - 1 + r, gx = xo - 1 + xc;
        unsigned short v = 0;
        if (gy >= 0 && gy < H_ && gx >= 0 && gx < W_)
            v = xT[((size_t)(((b << 6) + gy) << 6) + gx) * 256 + c];
        win[i][c] = v;
    }
    float w9[9];
#pragma unroll
    for (int j = 0; j < 9; ++j) w9[j] = dwc_w[c * 9 + j];
    float lw = ln_w[c], lb = ln_b[c], fd = fcd_w[c], fa = fca_w[c];
    __syncthreads();

    int lane = c & 63, wid = c >> 6;
#pragma unroll
    for (int p = 0; p < 8; ++p) {
        int pr = p & 1;
        float acc = 0.f;
#pragma unroll
        for (int j = 0; j < 9; ++j) {
            int r = j / 3, xc = p + (j - r * 3);
            acc += w9[j] * bf2f(win[r * 10 + xc][c]);
        }
        float s1 = acc, s2 = acc * acc;
#pragma unroll
        for (int off = 32; off >= 1; off >>= 1) {
            s1 += __shfl_down(s1, off);
            s2 += __shfl_down(s2, off);
        }
        if (lane == 0) { red[pr][0][wid] = s1; red[pr][1][wid] = s2; }
        __syncthreads();
        float tot1 = red[pr][0][0] + red[pr][0][1] + red[pr][0][2] + red[pr][0][3];
        float tot2 = red[pr][1][0] + red[pr][1][1] + red[pr][1][2] + red[pr][1][3];
        float mu  = tot1 * (1.f / 256.f);
        float var = tot2 * (1.f / 256.f) - mu * mu;
        float hn = (acc - mu) * rsqrtf(var + 1e-5f) * lw + lb;
        hn = fmaxf(hn, 0.f);
        float d1 = hn * fd, d2 = hn * fa;
#pragma unroll
        for (int off = 32; off >= 1; off >>= 1) {
            d1 += __shfl_down(d1, off);
            d2 += __shfl_down(d2, off);
        }
        if (lane == 0) { red[pr][2][wid] = d1; red[pr][3][wid] = d2; }
        __syncthreads();
        if (c == 0) {
            float r0 = red[pr][2][0] + red[pr][2][1] + red[pr][2][2] + red[pr][2][3];
            r0 = fmaxf(r0, 0.f);
            float t0 = red[pr][3][0] + red[pr][3][1] + red[pr][3][2] + red[pr][3][3];
            float theta = t0 / (1.f + fabsf(t0)) * 0.017453292519943295f;
            int pos = ((b << 6) + y) * 64 + xo + p;
            OX[pos] = r0 * cosf(theta);
            OY[pos] = r0 * sinf(theta);
        }
    }
}

// ---------------- K3: pack dconv_w (Co,C,3,3) f32 -> Bt (N=256 x K=2304) bf16 --------
__global__ void k_packB(const float* __restrict__ w, unsigned short* __restrict__ Bt)
{
    int idx = blockIdx.x * 256 + threadIdx.x;
    int o = idx / 2304, kk = idx - o * 2304;
    int k = kk >> 8, c = kk & 255;
    Bt[idx] = f2bf(w[(o * C_ + c) * 9 + k]);
}

// ---------------- K4: implicit GEMM deformable conv ----------------------------------
// 1024 blocks x 512 threads. Block = 32 positions x 128 outputs (N split in halves).
// 8 waves: wave w = 32 pos x 16 outs (2 M-frags x 1 N-frag, acc = 8 VGPR).
// 4 blocks/CU (LDS 32KB) x 8 waves = 32 waves/CU target occupancy.
__launch_bounds__(512, 8)
__global__ void k_main(const unsigned short* __restrict__ xT,
                       const float* __restrict__ OX, const float* __restrict__ OY,
                       const unsigned short* __restrict__ Bt,
                       const float* __restrict__ bias,
                       float* __restrict__ out)
{
    __shared__ __align__(16) unsigned char smem[32768];  // A dbuf 2x16KB / epilogue 17KB

    int tid = threadIdx.x;
    int bi = blockIdx.x;
    int g = ((bi & 7) << 7) | (bi >> 3);   // XCD-chunked: consecutive g share an XCD
    int tile = g >> 1;                     // 0..511 position tile
    int n0 = (g & 1) << 7;                 // 0 or 128
    int p0 = tile << 5;
    int b = p0 >> 12;
    int y = (p0 >> 6) & 63;
    int xh = p0 & 63;

    int lane = tid & 63, wid = tid >> 6;
    int l15 = lane & 15, l4 = lane >> 4;

    f32x4 acc[2];
#pragma unroll
    for (int m = 0; m < 2; ++m) {
        acc[m].x = 0.f; acc[m].y = 0.f; acc[m].z = 0.f; acc[m].w = 0.f;
    }

    int gpos = tid >> 4;              // 0..31 position
    int cblk = (tid & 15) << 4;       // 16-channel chunk
    const unsigned short* xb = xT + (size_t)b * HW_ * C_;
    const unsigned short* brow = Bt + (size_t)(n0 + wid * 16 + l15) * 2304 + (l4 << 3);
    unsigned swzr = ((unsigned)gpos & 7u) << 4;
    unsigned rowb = (unsigned)gpos * 512u;
    float ox = OX[p0 + gpos], oy = OY[p0 + gpos];

#define GADDR(k)                                                                  \
        int ky = (k) / 3, kx = (k) - ky * 3;                                      \
        float dyv = ((k) <= 4) ? ox : oy;                                         \
        float dxv = ((k) <= 3) ? ox : oy;                                         \
        float py = (float)(y - 1 + ky) + dyv;                                     \
        float px = (float)(xh + gpos - 1 + kx) + dxv;                             \
        float y0f = floorf(py), x0f = floorf(px);                                 \
        int y0 = (int)y0f, x0 = (int)x0f;                                         \
        int y1 = y0 + 1, x1 = x0 + 1;                                             \
        float wy1 = py - y0f, wy0 = 1.f - wy1;                                    \
        float wx1 = px - x0f, wx0 = 1.f - wx1;                                    \
        float vy0 = (y0 >= 0 && y0 < H_) ? 1.f : 0.f;                             \
        float vy1 = (y1 >= 0 && y1 < H_) ? 1.f : 0.f;                             \
        float vx0 = (x0 >= 0 && x0 < W_) ? 1.f : 0.f;                             \
        float vx1 = (x1 >= 0 && x1 < W_) ? 1.f : 0.f;                             \
        w00 = wy0 * wx0 * vy0 * vx0; w01 = wy0 * wx1 * vy0 * vx1;                 \
        w10 = wy1 * wx0 * vy1 * vx0; w11 = wy1 * wx1 * vy1 * vx1;                 \
        int y0c = min(max(y0, 0), H_ - 1), y1c = min(max(y1, 0), H_ - 1);         \
        int x0c = min(max(x0, 0), W_ - 1), x1c = min(max(x1, 0), W_ - 1);         \
        o00 = (unsigned)((y0c << 6) + x0c) * 256u + (unsigned)cblk;               \
        o01 = (unsigned)((y0c << 6) + x1c) * 256u + (unsigned)cblk;               \
        o10 = (unsigned)((y1c << 6) + x0c) * 256u + (unsigned)cblk;               \
        o11 = (unsigned)((y1c << 6) + x1c) * 256u + (unsigned)cblk;

#define GLOAD(G, add)                                                             \
        G[0] = *(const short8*)(xb + o00 + (add));                                \
        G[1] = *(const short8*)(xb + o01 + (add));                                \
        G[2] = *(const short8*)(xb + o10 + (add));                                \
        G[3] = *(const short8*)(xb + o11 + (add));

#define LERP8(G, add, buf)                                                        \
    {   short8 res;                                                               \
        _Pragma("unroll")                                                         \
        for (int j = 0; j < 8; ++j) {                                             \
            float a = bf2f((unsigned short)G[0][j]) * w00                         \
                    + bf2f((unsigned short)G[1][j]) * w01                         \
                    + bf2f((unsigned short)G[2][j]) * w10                         \
                    + bf2f((unsigned short)G[3][j]) * w11;                        \
            res[j] = (short)f2bf(a);                                              \
        }                                                                         \
        *(short8*)(smem + (unsigned)(buf) * 16384u + rowb +                       \
                   ((((unsigned)(cblk + (add))) * 2u) ^ swzr)) = res;             \
    }

    // ---- prologue: gather tap 0 into buf0 ----
    {
        unsigned o00, o01, o10, o11;
        float w00, w01, w10, w11;
        GADDR(0);
        short8 glo[4], ghi[4];
        GLOAD(glo, 0);
        GLOAD(ghi, 8);
        LERP8(glo, 0, 0);
        LERP8(ghi, 8, 0);
    }
    __syncthreads();

#pragma unroll
    for (int k = 0; k < 9; ++k) {
        int t = k & 1;
        unsigned o00, o01, o10, o11;
        float w00, w01, w10, w11;
        short8 glo[4], ghi[4];
        if (k < 8) {
            GADDR(k + 1);
            GLOAD(glo, 0);                        // issue lo gather early
        }
        const unsigned short* bk = brow + (k << 8);
        unsigned abase = (unsigned)t * 16384u;
#pragma unroll
        for (int ks = 0; ks < 8; ++ks) {
            if (ks == 4 && k < 8) { GLOAD(ghi, 8); }   // issue hi gather midway
            unsigned coff0 = (unsigned)(ks * 64 + (l4 << 4)) ^ (((unsigned)l15 & 7u) << 4);
            short8 a0 = *(const short8*)(smem + abase + (unsigned)l15 * 512u + coff0);
            short8 a1 = *(const short8*)(smem + abase + (unsigned)(16 + l15) * 512u + coff0);
            short8 bf = *(const short8*)(bk + ks * 32);
            acc[0] = __builtin_amdgcn_mfma_f32_16x16x32_bf16(a0, bf, acc[0], 0, 0, 0);
            acc[1] = __builtin_amdgcn_mfma_f32_16x16x32_bf16(a1, bf, acc[1], 0, 0, 0);
        }
        if (k < 8) {
            LERP8(glo, 0, t ^ 1);
            LERP8(ghi, 8, t ^ 1);
        }
        __syncthreads();
    }

    // ---- epilogue: LDS transpose (pad 133 vs bank aliasing) then NCHW stores ----
    float* epi = (float*)smem;
#pragma unroll
    for (int m = 0; m < 2; ++m)
#pragma unroll
        for (int i = 0; i < 4; ++i) {
            int row = m * 16 + l4 * 4 + i;        // position 0..31
            int col = wid * 16 + l15;             // local out 0..127
            epi[row * 133 + col] = acc[m][i];
        }
    __syncthreads();
    int o  = tid >> 2;                 // 0..127
    int wq = (tid & 3) << 3;           // 0,8,16,24
    float bv = bias[n0 + o];
    float* orow = out + (size_t)(((b * CO_ + n0 + o) * H_ + y) * W_) + xh + wq;
#pragma unroll
    for (int j = 0; j < 8; j += 4) {
        f32x4 v;
        v.x = epi[(wq + j + 0) * 133 + o] + bv;
        v.y = epi[(wq + j + 1) * 133 + o] + bv;
        v.z = epi[(wq + j + 2) * 133 + o] + bv;
        v.w = epi[(wq + j + 3) * 133 + o] + bv;
        *(f32x4*)(orow + j) = v;
    }
}

extern "C" void kernel_launch(void* const* d_in, const int* in_sizes, int n_in,
                              void* d_out, int out_size, void* d_ws, size_t ws_size,
                              hipStream_t stream) {
    const float* x      = (const float*)d_in[0];
    const float* dwc_w  = (const float*)d_in[1];
    const float* ln_w   = (const float*)d_in[2];
    const float* ln_b   = (const float*)d_in[3];
    const float* fcd_w  = (const float*)d_in[4];
    const float* fca_w  = (const float*)d_in[5];
    const float* dconv_w= (const float*)d_in[6];
    const float* dconv_b= (const float*)d_in[7];
    float* out = (float*)d_out;

    unsigned char* ws = (unsigned char*)d_ws;
    unsigned short* xT = (unsigned short*)(ws);                 // 8 MB bf16 NHWC
    float* OX = (float*)(ws + 8388608);
    float* OY = (float*)(ws + 8454144);
    unsigned short* Bt = (unsigned short*)(ws + 8519680);

    k_transpose<<<1024, 256, 0, stream>>>(x, xT);
    k_packB<<<2304, 256, 0, stream>>>(dconv_w, Bt);
    k_offsets<<<2048, 256, 0, stream>>>(xT, dwc_w, ln_w, ln_b, fcd_w, fca_w, OX, OY);
    k_main<<<1024, 512, 0, stream>>>(xT, OX, OY, Bt, dconv_b, out);
}

// Round 6
// 124.969 us; speedup vs baseline: 1.5179x; 1.5179x over previous
//
#include <hip/hip_runtime.h>
#include <hip/hip_bf16.h>

#define B_   4
#define C_   256
#define CO_  256
#define H_   64
#define W_   64
#define HW_  4096

typedef __attribute__((ext_vector_type(8))) short short8;
typedef __attribute__((ext_vector_type(4))) float f32x4;

static __device__ __forceinline__ unsigned short f2bf(float f) {
    unsigned u = __builtin_bit_cast(unsigned, f);
    unsigned r = (u + 0x7fffu + ((u >> 16) & 1u)) >> 16;
    return (unsigned short)r;
}
static __device__ __forceinline__ float bf2f(unsigned short s) {
    unsigned u = ((unsigned)s) << 16;
    return __builtin_bit_cast(float, u);
}

// ---------------- K1: NCHW f32 -> NHWC bf16 transpose (32hw x 128c tiles) ------------
__global__ void k_transpose(const float* __restrict__ x, unsigned short* __restrict__ xT)
{
    __shared__ float t[32][136];
    int bid = blockIdx.x;            // 1024 = b(4) * hwT(128) * cT(2)
    int b   = bid >> 8;
    int rem = bid & 255;
    int hwT = rem >> 1, cT = rem & 1;
    int hw0 = hwT * 32, c0 = cT * 128;
    int tid = threadIdx.x;
    const float* src = x + (size_t)b * C_ * HW_;
    {
        int hwi = tid & 31, cr = tid >> 5;
#pragma unroll
        for (int ps = 0; ps < 16; ++ps) {
            int c = cr + ps * 8;
            t[hwi][c] = src[(size_t)(c0 + c) * HW_ + hw0 + hwi];
        }
    }
    __syncthreads();
    {
        int c4 = (tid & 31) * 4, hwr = tid >> 5;
        unsigned short* dst = xT + (size_t)(((b << 12) + hw0) * 256) + c0 + c4;
#pragma unroll
        for (int ps = 0; ps < 4; ++ps) {
            int hw = hwr + ps * 8;
            f32x4 v = *(const f32x4*)&t[hw][c4];
            ushort4 u;
            u.x = f2bf(v.x); u.y = f2bf(v.y); u.z = f2bf(v.z); u.w = f2bf(v.w);
            *(ushort4*)(dst + (size_t)hw * 256) = u;
        }
    }
}

// ---------------- K2: offsets — 8 positions per block, LDS window --------------------
__global__ void k_offsets(const unsigned short* __restrict__ xT,
                          const float* __restrict__ dwc_w,
                          const float* __restrict__ ln_w,
                          const float* __restrict__ ln_b,
                          const float* __restrict__ fcd_w,
                          const float* __restrict__ fca_w,
                          float* __restrict__ OX, float* __restrict__ OY)
{
    __shared__ unsigned short win[30][256];   // [r*10+xc][ch]
    __shared__ float red[2][4][16];
    int bi = blockIdx.x;
    int oct = ((bi & 7) << 8) | (bi >> 3);    // XCD swizzle
    int b = oct >> 9, rem = oct & 511, y = rem >> 3, xo = (rem & 7) << 3;
    int c = threadIdx.x;

    for (int i = 0; i < 30; ++i) {
        int r = i / 10, xc = i - r * 10;
        int gy = y - 1 + r, gx = xo - 1 + xc;
        unsigned short v = 0;
        if (gy >= 0 && gy < H_ && gx >= 0 && gx < W_)
            v = xT[((size_t)(((b << 6) + gy) << 6) + gx) * 256 + c];
        win[i][c] = v;
    }
    float w9[9];
#pragma unroll
    for (int j = 0; j < 9; ++j) w9[j] = dwc_w[c * 9 + j];
    float lw = ln_w[c], lb = ln_b[c], fd = fcd_w[c], fa = fca_w[c];
    __syncthreads();

    int lane = c & 63, wid = c >> 6;
#pragma unroll
    for (int p = 0; p < 8; ++p) {
        int pr = p & 1;
        float acc = 0.f;
#pragma unroll
        for (int j = 0; j < 9; ++j) {
            int r = j / 3, xc = p + (j - r * 3);
            acc += w9[j] * bf2f(win[r * 10 + xc][c]);
        }
        float s1 = acc, s2 = acc * acc;
#pragma unroll
        for (int off = 32; off >= 1; off >>= 1) {
            s1 += __shfl_down(s1, off);
            s2 += __shfl_down(s2, off);
        }
        if (lane == 0) { red[pr][0][wid] = s1; red[pr][1][wid] = s2; }
        __syncthreads();
        float tot1 = red[pr][0][0] + red[pr][0][1] + red[pr][0][2] + red[pr][0][3];
        float tot2 = red[pr][1][0] + red[pr][1][1] + red[pr][1][2] + red[pr][1][3];
        float mu  = tot1 * (1.f / 256.f);
        float var = tot2 * (1.f / 256.f) - mu * mu;
        float hn = (acc - mu) * rsqrtf(var + 1e-5f) * lw + lb;
        hn = fmaxf(hn, 0.f);
        float d1 = hn * fd, d2 = hn * fa;
#pragma unroll
        for (int off = 32; off >= 1; off >>= 1) {
            d1 += __shfl_down(d1, off);
            d2 += __shfl_down(d2, off);
        }
        if (lane == 0) { red[pr][2][wid] = d1; red[pr][3][wid] = d2; }
        __syncthreads();
        if (c == 0) {
            float r0 = red[pr][2][0] + red[pr][2][1] + red[pr][2][2] + red[pr][2][3];
            r0 = fmaxf(r0, 0.f);
            float t0 = red[pr][3][0] + red[pr][3][1] + red[pr][3][2] + red[pr][3][3];
            float theta = t0 / (1.f + fabsf(t0)) * 0.017453292519943295f;
            int pos = ((b << 6) + y) * 64 + xo + p;
            OX[pos] = r0 * cosf(theta);
            OY[pos] = r0 * sinf(theta);
        }
    }
}

// ---------------- K3: pack dconv_w (Co,C,3,3) f32 -> Bt (N=256 x K=2304) bf16 --------
__global__ void k_packB(const float* __restrict__ w, unsigned short* __restrict__ Bt)
{
    int idx = blockIdx.x * 256 + threadIdx.x;
    int o = idx / 2304, kk = idx - o * 2304;
    int k = kk >> 8, c = kk & 255;
    Bt[idx] = f2bf(w[(o * C_ + c) * 9 + k]);
}

// ---------------- K4: implicit GEMM deformable conv ----------------------------------
// 512 blocks x 512 threads. Block = full row (64 pos) x 128 outs.
// Wave = 64 pos (4 M-frags) x 16 outs (1 N-frag): each B frag feeds 4 MFMAs.
// LDS: 2 x 32KB A dbuf; 2 blocks/CU.
__launch_bounds__(512, 4)
__global__ void k_main(const unsigned short* __restrict__ xT,
                       const float* __restrict__ OX, const float* __restrict__ OY,
                       const unsigned short* __restrict__ Bt,
                       const float* __restrict__ bias,
                       float* __restrict__ out)
{
    __shared__ __align__(16) unsigned char smem[65536];  // A dbuf 2x32KB / epilogue 34KB

    int tid = threadIdx.x;
    int bi = blockIdx.x;
    int g = ((bi & 7) << 6) | (bi >> 3);   // XCD-chunked; pair (2g,2g+1) = same tile
    int tile = g >> 1;                     // 0..255 : (b, y) row
    int n0 = (g & 1) << 7;                 // 0 or 128
    int b = tile >> 6;
    int y = tile & 63;

    int lane = tid & 63, wid = tid >> 6;
    int l15 = lane & 15, l4 = lane >> 4;

    f32x4 acc[4];
#pragma unroll
    for (int m = 0; m < 4; ++m) {
        acc[m].x = 0.f; acc[m].y = 0.f; acc[m].z = 0.f; acc[m].w = 0.f;
    }

    int gpos = tid >> 3;              // 0..63 : position (x coordinate)
    int cblk = (tid & 7) << 5;        // 32-channel chunk per thread
    const unsigned short* xb = xT + (size_t)b * HW_ * C_;
    const unsigned short* brow = Bt + (size_t)(n0 + wid * 16 + l15) * 2304 + (l4 << 3);
    unsigned swzr = ((unsigned)gpos & 7u) << 4;
    unsigned rowb = (unsigned)gpos * 512u;
    float ox = OX[(tile << 6) + gpos], oy = OY[(tile << 6) + gpos];

#define GADDR(k)                                                                  \
        int ky = (k) / 3, kx = (k) - ky * 3;                                      \
        float dyv = ((k) <= 4) ? ox : oy;                                         \
        float dxv = ((k) <= 3) ? ox : oy;                                         \
        float py = (float)(y - 1 + ky) + dyv;                                     \
        float px = (float)(gpos - 1 + kx) + dxv;                                  \
        float y0f = floorf(py), x0f = floorf(px);                                 \
        int y0 = (int)y0f, x0 = (int)x0f;                                         \
        int y1 = y0 + 1, x1 = x0 + 1;                                             \
        float wy1 = py - y0f, wy0 = 1.f - wy1;                                    \
        float wx1 = px - x0f, wx0 = 1.f - wx1;                                    \
        float vy0 = (y0 >= 0 && y0 < H_) ? 1.f : 0.f;                             \
        float vy1 = (y1 >= 0 && y1 < H_) ? 1.f : 0.f;                             \
        float vx0 = (x0 >= 0 && x0 < W_) ? 1.f : 0.f;                             \
        float vx1 = (x1 >= 0 && x1 < W_) ? 1.f : 0.f;                             \
        w00 = wy0 * wx0 * vy0 * vx0; w01 = wy0 * wx1 * vy0 * vx1;                 \
        w10 = wy1 * wx0 * vy1 * vx0; w11 = wy1 * wx1 * vy1 * vx1;                 \
        int y0c = min(max(y0, 0), H_ - 1), y1c = min(max(y1, 0), H_ - 1);         \
        int x0c = min(max(x0, 0), W_ - 1), x1c = min(max(x1, 0), W_ - 1);         \
        o00 = (unsigned)((y0c << 6) + x0c) * 256u + (unsigned)cblk;               \
        o01 = (unsigned)((y0c << 6) + x1c) * 256u + (unsigned)cblk;               \
        o10 = (unsigned)((y1c << 6) + x0c) * 256u + (unsigned)cblk;               \
        o11 = (unsigned)((y1c << 6) + x1c) * 256u + (unsigned)cblk;

    // gather one 8-channel sub-chunk (cc in {0,8,16,24}) and write to LDS buf
#define GATHER8(cc, buf)                                                          \
    {   short8 r00 = *(const short8*)(xb + o00 + (cc));                           \
        short8 r01 = *(const short8*)(xb + o01 + (cc));                           \
        short8 r10 = *(const short8*)(xb + o10 + (cc));                           \
        short8 r11 = *(const short8*)(xb + o11 + (cc));                           \
        short8 res;                                                               \
        _Pragma("unroll")                                                         \
        for (int j = 0; j < 8; ++j) {                                             \
            float a = bf2f((unsigned short)r00[j]) * w00                          \
                    + bf2f((unsigned short)r01[j]) * w01                          \
                    + bf2f((unsigned short)r10[j]) * w10                          \
                    + bf2f((unsigned short)r11[j]) * w11;                         \
            res[j] = (short)f2bf(a);                                              \
        }                                                                         \
        *(short8*)(smem + (unsigned)(buf) * 32768u + rowb +                       \
                   ((((unsigned)(cblk + (cc))) * 2u) ^ swzr)) = res;              \
    }

#define GATHER_TAP(k, buf)                                                        \
    {   unsigned o00, o01, o10, o11;                                              \
        float w00, w01, w10, w11;                                                 \
        GADDR(k);                                                                 \
        GATHER8(0, buf);                                                          \
        GATHER8(8, buf);                                                          \
        GATHER8(16, buf);                                                         \
        GATHER8(24, buf);                                                         \
    }

    // ---- prologue: tap 0 into buf0 ----
    GATHER_TAP(0, 0);
    __syncthreads();

#pragma unroll
    for (int k = 0; k < 9; ++k) {
        int t = k & 1;
        // ---- MFMA phase on buf t, tap k ----
        {
            const unsigned short* bk = brow + (k << 8);
            unsigned abase = (unsigned)t * 32768u;
#pragma unroll
            for (int ks = 0; ks < 8; ++ks) {
                short8 bf = *(const short8*)(bk + ks * 32);
                unsigned coff = (unsigned)(ks * 64 + (l4 << 4)) ^ (((unsigned)l15 & 7u) << 4);
#pragma unroll
                for (int mf = 0; mf < 4; ++mf) {
                    short8 a = *(const short8*)(smem + abase +
                                 (unsigned)(mf * 16 + l15) * 512u + coff);
                    acc[mf] = __builtin_amdgcn_mfma_f32_16x16x32_bf16(a, bf, acc[mf], 0, 0, 0);
                }
            }
        }
        // ---- gather next tap into buf t^1 (overlaps MFMA via scheduler) ----
        if (k < 8) {
            GATHER_TAP(k + 1, t ^ 1);
        }
        __syncthreads();
    }

    // ---- epilogue: LDS transpose (stride 133) then coalesced NCHW stores ----
    float* epi = (float*)smem;
#pragma unroll
    for (int mf = 0; mf < 4; ++mf)
#pragma unroll
        for (int i = 0; i < 4; ++i) {
            int row = mf * 16 + l4 * 4 + i;      // position 0..63
            int col = wid * 16 + l15;            // local out 0..127
            epi[row * 133 + col] = acc[mf][i];
        }
    __syncthreads();
    int o  = tid >> 2;                 // 0..127
    int wq = (tid & 3) << 4;           // 0,16,32,48
    float bv = bias[n0 + o];
    float* orow = out + (size_t)(((b * CO_ + n0 + o) * H_ + y) * W_) + wq;
#pragma unroll
    for (int j = 0; j < 16; j += 4) {
        f32x4 v;
        v.x = epi[(wq + j + 0) * 133 + o] + bv;
        v.y = epi[(wq + j + 1) * 133 + o] + bv;
        v.z = epi[(wq + j + 2) * 133 + o] + bv;
        v.w = epi[(wq + j + 3) * 133 + o] + bv;
        *(f32x4*)(orow + j) = v;
    }
}

extern "C" void kernel_launch(void* const* d_in, const int* in_sizes, int n_in,
                              void* d_out, int out_size, void* d_ws, size_t ws_size,
                              hipStream_t stream) {
    const float* x      = (const float*)d_in[0];
    const float* dwc_w  = (const float*)d_in[1];
    const float* ln_w   = (const float*)d_in[2];
    const float* ln_b   = (const float*)d_in[3];
    const float* fcd_w  = (const float*)d_in[4];
    const float* fca_w  = (const float*)d_in[5];
    const float* dconv_w= (const float*)d_in[6];
    const float* dconv_b= (const float*)d_in[7];
    float* out = (float*)d_out;

    unsigned char* ws = (unsigned char*)d_ws;
    unsigned short* xT = (unsigned short*)(ws);                 // 8 MB bf16 NHWC
    float* OX = (float*)(ws + 8388608);
    float* OY = (float*)(ws + 8454144);
    unsigned short* Bt = (unsigned short*)(ws + 8519680);

    k_transpose<<<1024, 256, 0, stream>>>(x, xT);
    k_packB<<<2304, 256, 0, stream>>>(dconv_w, Bt);
    k_offsets<<<2048, 256, 0, stream>>>(xT, dwc_w, ln_w, ln_b, fcd_w, fca_w, OX, OY);
    k_main<<<512, 512, 0, stream>>>(xT, OX, OY, Bt, dconv_b, out);
}

// Round 7
// 90.318 us; speedup vs baseline: 2.1003x; 1.3837x over previous
//
#include <hip/hip_runtime.h>
#include <hip/hip_bf16.h>

#define B_   4
#define C_   256
#define CO_  256
#define H_   64
#define W_   64
#define HW_  4096

typedef __attribute__((ext_vector_type(8))) short short8;
typedef __attribute__((ext_vector_type(4))) float f32x4;

static __device__ __forceinline__ unsigned short f2bf(float f) {
    unsigned u = __builtin_bit_cast(unsigned, f);
    unsigned r = (u + 0x7fffu + ((u >> 16) & 1u)) >> 16;
    return (unsigned short)r;
}
static __device__ __forceinline__ float bf2f(unsigned short s) {
    unsigned u = ((unsigned)s) << 16;
    return __builtin_bit_cast(float, u);
}

// ---------------- K1: NCHW f32 -> NHWC bf16 transpose (32hw x 128c tiles) ------------
__global__ void k_transpose(const float* __restrict__ x, unsigned short* __restrict__ xT)
{
    __shared__ float t[32][136];
    int bid = blockIdx.x;            // 1024 = b(4) * hwT(128) * cT(2)
    int b   = bid >> 8;
    int rem = bid & 255;
    int hwT = rem >> 1, cT = rem & 1;
    int hw0 = hwT * 32, c0 = cT * 128;
    int tid = threadIdx.x;
    const float* src = x + (size_t)b * C_ * HW_;
    {
        int hwi = tid & 31, cr = tid >> 5;
#pragma unroll
        for (int ps = 0; ps < 16; ++ps) {
            int c = cr + ps * 8;
            t[hwi][c] = src[(size_t)(c0 + c) * HW_ + hw0 + hwi];
        }
    }
    __syncthreads();
    {
        int c4 = (tid & 31) * 4, hwr = tid >> 5;
        unsigned short* dst = xT + (size_t)(((b << 12) + hw0) * 256) + c0 + c4;
#pragma unroll
        for (int ps = 0; ps < 4; ++ps) {
            int hw = hwr + ps * 8;
            f32x4 v = *(const f32x4*)&t[hw][c4];
            ushort4 u;
            u.x = f2bf(v.x); u.y = f2bf(v.y); u.z = f2bf(v.z); u.w = f2bf(v.w);
            *(ushort4*)(dst + (size_t)hw * 256) = u;
        }
    }
}

// ---------------- K2: offsets — 8 positions per block, LDS window --------------------
__global__ void k_offsets(const unsigned short* __restrict__ xT,
                          const float* __restrict__ dwc_w,
                          const float* __restrict__ ln_w,
                          const float* __restrict__ ln_b,
                          const float* __restrict__ fcd_w,
                          const float* __restrict__ fca_w,
                          float* __restrict__ OX, float* __restrict__ OY)
{
    __shared__ unsigned short win[30][256];   // [r*10+xc][ch]
    __shared__ float red[2][4][16];
    int bi = blockIdx.x;
    int oct = ((bi & 7) << 8) | (bi >> 3);    // XCD swizzle
    int b = oct >> 9, rem = oct & 511, y = rem >> 3, xo = (rem & 7) << 3;
    int c = threadIdx.x;

    for (int i = 0; i < 30; ++i) {
        int r = i / 10, xc = i - r * 10;
        int gy = y - 1 + r, gx = xo - 1 + xc;
        unsigned short v = 0;
        if (gy >= 0 && gy < H_ && gx >= 0 && gx < W_)
            v = xT[((size_t)(((b << 6) + gy) << 6) + gx) * 256 + c];
        win[i][c] = v;
    }
    float w9[9];
#pragma unroll
    for (int j = 0; j < 9; ++j) w9[j] = dwc_w[c * 9 + j];
    float lw = ln_w[c], lb = ln_b[c], fd = fcd_w[c], fa = fca_w[c];
    __syncthreads();

    int lane = c & 63, wid = c >> 6;
#pragma unroll
    for (int p = 0; p < 8; ++p) {
        int pr = p & 1;
        float acc = 0.f;
#pragma unroll
        for (int j = 0; j < 9; ++j) {
            int r = j / 3, xc = p + (j - r * 3);
            acc += w9[j] * bf2f(win[r * 10 + xc][c]);
        }
        float s1 = acc, s2 = acc * acc;
#pragma unroll
        for (int off = 32; off >= 1; off >>= 1) {
            s1 += __shfl_down(s1, off);
            s2 += __shfl_down(s2, off);
        }
        if (lane == 0) { red[pr][0][wid] = s1; red[pr][1][wid] = s2; }
        __syncthreads();
        float tot1 = red[pr][0][0] + red[pr][0][1] + red[pr][0][2] + red[pr][0][3];
        float tot2 = red[pr][1][0] + red[pr][1][1] + red[pr][1][2] + red[pr][1][3];
        float mu  = tot1 * (1.f / 256.f);
        float var = tot2 * (1.f / 256.f) - mu * mu;
        float hn = (acc - mu) * rsqrtf(var + 1e-5f) * lw + lb;
        hn = fmaxf(hn, 0.f);
        float d1 = hn * fd, d2 = hn * fa;
#pragma unroll
        for (int off = 32; off >= 1; off >>= 1) {
            d1 += __shfl_down(d1, off);
            d2 += __shfl_down(d2, off);
        }
        if (lane == 0) { red[pr][2][wid] = d1; red[pr][3][wid] = d2; }
        __syncthreads();
        if (c == 0) {
            float r0 = red[pr][2][0] + red[pr][2][1] + red[pr][2][2] + red[pr][2][3];
            r0 = fmaxf(r0, 0.f);
            float t0 = red[pr][3][0] + red[pr][3][1] + red[pr][3][2] + red[pr][3][3];
            float theta = t0 / (1.f + fabsf(t0)) * 0.017453292519943295f;
            int pos = ((b << 6) + y) * 64 + xo + p;
            OX[pos] = r0 * cosf(theta);
            OY[pos] = r0 * sinf(theta);
        }
    }
}

// ---------------- K3: pack dconv_w -> fragment-ordered Bt ----------------------------
// Bt index = ((((k*16+og)*8+ks)*16+l15)*4+l4)*8 + j
//  out o = og*16+l15 ; channel c = ks*32 + l4*8 + j ; tap k.
// A wave's per-(k,ks) load = 64 lanes x 16B = 1KB fully contiguous.
__global__ void k_packB(const float* __restrict__ w, unsigned short* __restrict__ Bt)
{
    int e = blockIdx.x * 256 + threadIdx.x;    // 589824 total
    int j   = e & 7;
    int l4  = (e >> 3) & 3;
    int l15 = (e >> 5) & 15;
    int ks  = (e >> 9) & 7;
    int og  = (e >> 12) & 15;
    int k   = e >> 16;
    int o = og * 16 + l15;
    int c = ks * 32 + l4 * 8 + j;
    Bt[e] = f2bf(w[(o * C_ + c) * 9 + k]);
}

// ---------------- K4: implicit GEMM deformable conv ----------------------------------
// 512 blocks x 512 threads. Block = full row (64 pos) x 128 outs.
// Wave = 64 pos (4 M-frags) x 16 outs; every memory instr minimal-transaction:
//  gather: per-instr 8 pos x 128B contiguous; LDS write conflict-free; B 1KB/instr.
__launch_bounds__(512, 4)
__global__ void k_main(const unsigned short* __restrict__ xT,
                       const float* __restrict__ OX, const float* __restrict__ OY,
                       const unsigned short* __restrict__ Bt,
                       const float* __restrict__ bias,
                       float* __restrict__ out)
{
    __shared__ __align__(16) unsigned char smem[65536];  // A dbuf 2x32KB / epilogue 34KB

    int tid = threadIdx.x;
    int bi = blockIdx.x;
    int g = ((bi & 7) << 6) | (bi >> 3);   // XCD-chunked
    int tile = g >> 1;                     // 0..255 : (b, y) row
    int n0g = g & 1;                       // N half
    int b = tile >> 6;
    int y = tile & 63;

    int lane = tid & 63, wid = tid >> 6;
    int l15 = lane & 15, l4 = lane >> 4;

    f32x4 acc[4];
#pragma unroll
    for (int m = 0; m < 4; ++m) {
        acc[m].x = 0.f; acc[m].y = 0.f; acc[m].z = 0.f; acc[m].w = 0.f;
    }

    int gpos = tid >> 3;                     // 0..63 : position (x coordinate)
    unsigned csub16 = ((unsigned)tid & 7u) << 4;   // byte offset of the 16B channel chunk
    const char* xbB = (const char*)(xT + (size_t)b * HW_ * C_);
    const unsigned short* bwave = Bt + (unsigned)(n0g * 8 + wid) * 4096u
                                     + (unsigned)(l15 * 32 + l4 * 8);
    unsigned rowb = (unsigned)gpos * 512u;
    unsigned swzoff = ((csub16 >> 4) ^ ((unsigned)gpos & 7u)) << 4;
    float ox = OX[(tile << 6) + gpos], oy = OY[(tile << 6) + gpos];

#define GADDR(k)                                                                  \
        int ky = (k) / 3, kx = (k) - ky * 3;                                      \
        float dyv = ((k) <= 4) ? ox : oy;                                         \
        float dxv = ((k) <= 3) ? ox : oy;                                         \
        float py = (float)(y - 1 + ky) + dyv;                                     \
        float px = (float)(gpos - 1 + kx) + dxv;                                  \
        float y0f = floorf(py), x0f = floorf(px);                                 \
        int y0 = (int)y0f, x0 = (int)x0f;                                         \
        int y1 = y0 + 1, x1 = x0 + 1;                                             \
        float wy1 = py - y0f, wy0 = 1.f - wy1;                                    \
        float wx1 = px - x0f, wx0 = 1.f - wx1;                                    \
        float vy0 = (y0 >= 0 && y0 < H_) ? 1.f : 0.f;                             \
        float vy1 = (y1 >= 0 && y1 < H_) ? 1.f : 0.f;                             \
        float vx0 = (x0 >= 0 && x0 < W_) ? 1.f : 0.f;                             \
        float vx1 = (x1 >= 0 && x1 < W_) ? 1.f : 0.f;                             \
        w00 = wy0 * wx0 * vy0 * vx0; w01 = wy0 * wx1 * vy0 * vx1;                 \
        w10 = wy1 * wx0 * vy1 * vx0; w11 = wy1 * wx1 * vy1 * vx1;                 \
        int y0c = min(max(y0, 0), H_ - 1), y1c = min(max(y1, 0), H_ - 1);         \
        int x0c = min(max(x0, 0), W_ - 1), x1c = min(max(x1, 0), W_ - 1);         \
        o00 = (unsigned)((y0c << 6) + x0c) * 512u + csub16;                       \
        o01 = (unsigned)((y0c << 6) + x1c) * 512u + csub16;                       \
        o10 = (unsigned)((y1c << 6) + x0c) * 512u + csub16;                       \
        o11 = (unsigned)((y1c << 6) + x1c) * 512u + csub16;

#define GATHER_TAP(k, buf)                                                        \
    {   unsigned o00, o01, o10, o11;                                              \
        float w00, w01, w10, w11;                                                 \
        GADDR(k);                                                                 \
        unsigned wb = (unsigned)(buf) * 32768u + rowb + swzoff;                   \
        _Pragma("unroll")                                                         \
        for (int cq = 0; cq < 4; ++cq) {                                          \
            short8 r00 = *(const short8*)(xbB + o00 + cq * 128);                  \
            short8 r01 = *(const short8*)(xbB + o01 + cq * 128);                  \
            short8 r10 = *(const short8*)(xbB + o10 + cq * 128);                  \
            short8 r11 = *(const short8*)(xbB + o11 + cq * 128);                  \
            uint4 pkv;                                                            \
            _Pragma("unroll")                                                     \
            for (int jj = 0; jj < 4; ++jj) {                                      \
                float a0 = bf2f((unsigned short)r00[2*jj]) * w00                  \
                         + bf2f((unsigned short)r01[2*jj]) * w01                  \
                         + bf2f((unsigned short)r10[2*jj]) * w10                  \
                         + bf2f((unsigned short)r11[2*jj]) * w11;                 \
                float a1 = bf2f((unsigned short)r00[2*jj+1]) * w00                \
                         + bf2f((unsigned short)r01[2*jj+1]) * w01                \
                         + bf2f((unsigned short)r10[2*jj+1]) * w10                \
                         + bf2f((unsigned short)r11[2*jj+1]) * w11;               \
                unsigned pko;                                                     \
                asm("v_cvt_pk_bf16_f32 %0, %1, %2" : "=v"(pko) : "v"(a0), "v"(a1)); \
                ((unsigned*)&pkv)[jj] = pko;                                      \
            }                                                                     \
            *(uint4*)(smem + wb + cq * 128) = pkv;                                \
        }                                                                         \
    }

    // ---- prologue: tap 0 into buf0 ----
    GATHER_TAP(0, 0);
    __syncthreads();

#pragma unroll
    for (int k = 0; k < 9; ++k) {
        int t = k & 1;
        // ---- MFMA phase on buf t, tap k ----
        {
            const unsigned short* bk = bwave + (unsigned)k * 65536u;
            unsigned abase = (unsigned)t * 32768u;
#pragma unroll
            for (int ks = 0; ks < 8; ++ks) {
                short8 bf = *(const short8*)(bk + ks * 512);
                unsigned coff = (unsigned)(ks * 64 + (l4 << 4)) ^ (((unsigned)l15 & 7u) << 4);
#pragma unroll
                for (int mf = 0; mf < 4; ++mf) {
                    short8 a = *(const short8*)(smem + abase +
                                 (unsigned)(mf * 16 + l15) * 512u + coff);
                    acc[mf] = __builtin_amdgcn_mfma_f32_16x16x32_bf16(a, bf, acc[mf], 0, 0, 0);
                }
            }
        }
        // ---- gather next tap into buf t^1 (overlaps MFMA via scheduler) ----
        if (k < 8) {
            GATHER_TAP(k + 1, t ^ 1);
        }
        __syncthreads();
    }

    // ---- epilogue: LDS transpose (stride 133) then coalesced NCHW stores ----
    float* epi = (float*)smem;
#pragma unroll
    for (int mf = 0; mf < 4; ++mf)
#pragma unroll
        for (int i = 0; i < 4; ++i) {
            int row = mf * 16 + l4 * 4 + i;      // position 0..63
            int col = wid * 16 + l15;            // local out 0..127
            epi[row * 133 + col] = acc[mf][i];
        }
    __syncthreads();
    int o  = tid >> 2;                 // 0..127
    int wq = (tid & 3) << 4;           // 0,16,32,48
    float bv = bias[n0g * 128 + o];
    float* orow = out + (size_t)(((b * CO_ + n0g * 128 + o) * H_ + y) * W_) + wq;
#pragma unroll
    for (int j = 0; j < 16; j += 4) {
        f32x4 v;
        v.x = epi[(wq + j + 0) * 133 + o] + bv;
        v.y = epi[(wq + j + 1) * 133 + o] + bv;
        v.z = epi[(wq + j + 2) * 133 + o] + bv;
        v.w = epi[(wq + j + 3) * 133 + o] + bv;
        *(f32x4*)(orow + j) = v;
    }
}

extern "C" void kernel_launch(void* const* d_in, const int* in_sizes, int n_in,
                              void* d_out, int out_size, void* d_ws, size_t ws_size,
                              hipStream_t stream) {
    const float* x      = (const float*)d_in[0];
    const float* dwc_w  = (const float*)d_in[1];
    const float* ln_w   = (const float*)d_in[2];
    const float* ln_b   = (const float*)d_in[3];
    const float* fcd_w  = (const float*)d_in[4];
    const float* fca_w  = (const float*)d_in[5];
    const float* dconv_w= (const float*)d_in[6];
    const float* dconv_b= (const float*)d_in[7];
    float* out = (float*)d_out;

    unsigned char* ws = (unsigned char*)d_ws;
    unsigned short* xT = (unsigned short*)(ws);                 // 8 MB bf16 NHWC
    float* OX = (float*)(ws + 8388608);
    float* OY = (float*)(ws + 8454144);
    unsigned short* Bt = (unsigned short*)(ws + 8519680);

    k_transpose<<<1024, 256, 0, stream>>>(x, xT);
    k_packB<<<2304, 256, 0, stream>>>(dconv_w, Bt);
    k_offsets<<<2048, 256, 0, stream>>>(xT, dwc_w, ln_w, ln_b, fcd_w, fca_w, OX, OY);
    k_main<<<512, 512, 0, stream>>>(xT, OX, OY, Bt, dconv_b, out);
}

// Round 8
// 81.983 us; speedup vs baseline: 2.3138x; 1.1017x over previous
//
#include <hip/hip_runtime.h>
#include <hip/hip_bf16.h>

#define B_   4
#define C_   256
#define CO_  256
#define H_   64
#define W_   64
#define HW_  4096

typedef __attribute__((ext_vector_type(8))) short short8;
typedef __attribute__((ext_vector_type(4))) float f32x4;
typedef __attribute__((ext_vector_type(2))) float f32x2;

static __device__ __forceinline__ unsigned short f2bf(float f) {
    unsigned u = __builtin_bit_cast(unsigned, f);
    unsigned r = (u + 0x7fffu + ((u >> 16) & 1u)) >> 16;
    return (unsigned short)r;
}
static __device__ __forceinline__ float bf2f(unsigned short s) {
    unsigned u = ((unsigned)s) << 16;
    return __builtin_bit_cast(float, u);
}
static __device__ __forceinline__ f32x2 pk_mul(f32x2 a, f32x2 b) {
    f32x2 d; asm("v_pk_mul_f32 %0, %1, %2" : "=v"(d) : "v"(a), "v"(b)); return d;
}
static __device__ __forceinline__ f32x2 pk_fma(f32x2 a, f32x2 b, f32x2 c) {
    f32x2 d; asm("v_pk_fma_f32 %0, %1, %2, %3" : "=v"(d) : "v"(a), "v"(b), "v"(c)); return d;
}
static __device__ __forceinline__ f32x2 pk_add(f32x2 a, f32x2 b) {
    f32x2 d; asm("v_pk_add_f32 %0, %1, %2" : "=v"(d) : "v"(a), "v"(b)); return d;
}
static __device__ __forceinline__ unsigned cvtpk(float a, float b) {
    unsigned r; asm("v_cvt_pk_bf16_f32 %0, %1, %2" : "=v"(r) : "v"(a), "v"(b)); return r;
}
static __device__ __forceinline__ f32x2 unpack_bf2(unsigned d) {
    f32x2 v;
    v.x = __builtin_bit_cast(float, d << 16);
    v.y = __builtin_bit_cast(float, d & 0xffff0000u);
    return v;
}

// ---------------- K1: NCHW f32 -> NHWC bf16 transpose (vectorized) -------------------
__global__ void k_transpose(const float* __restrict__ x, unsigned short* __restrict__ xT)
{
    __shared__ float t[32][132];     // 32 hw x 128 c (+4 pad)
    int bid = blockIdx.x;            // 1024 = b(4) * hwT(128) * cT(2)
    int b   = bid >> 8;
    int rem = bid & 255;
    int hwT = rem >> 1, cT = rem & 1;
    int hw0 = hwT * 32, c0 = cT * 128;
    int tid = threadIdx.x;
    const float* src = x + (size_t)b * C_ * HW_;
    {
        int hw4 = (tid & 7) << 2;        // 0..28
        int cr  = tid >> 3;              // 0..31
#pragma unroll
        for (int it = 0; it < 4; ++it) {
            int c = cr + it * 32;
            f32x4 v = *(const f32x4*)(src + (size_t)(c0 + c) * HW_ + hw0 + hw4);
            t[hw4 + 0][c] = v.x;
            t[hw4 + 1][c] = v.y;
            t[hw4 + 2][c] = v.z;
            t[hw4 + 3][c] = v.w;
        }
    }
    __syncthreads();
    {
        int c8  = (tid & 15) << 3;       // 0..120
        int hwr = tid >> 4;              // 0..15
        unsigned short* dst = xT + (size_t)(((b << 12) + hw0) * 256) + c0 + c8;
#pragma unroll
        for (int it = 0; it < 2; ++it) {
            int hw = hwr + it * 16;
            f32x4 va = *(const f32x4*)&t[hw][c8];
            f32x4 vb = *(const f32x4*)&t[hw][c8 + 4];
            uint4 u;
            u.x = cvtpk(va.x, va.y);
            u.y = cvtpk(va.z, va.w);
            u.z = cvtpk(vb.x, vb.y);
            u.w = cvtpk(vb.z, vb.w);
            *(uint4*)(dst + (size_t)hw * 256) = u;
        }
    }
}

// ---------------- K2: pack dconv_w -> fragment-ordered Bt ----------------------------
// Bt index = ((((k*16+og)*8+ks)*16+l15)*4+l4)*8 + j ; o = og*16+l15 ; c = ks*32+l4*8+j
__global__ void k_packB(const float* __restrict__ w, unsigned short* __restrict__ Bt)
{
    int e = blockIdx.x * 256 + threadIdx.x;    // 589824 total
    int j   = e & 7;
    int l4  = (e >> 3) & 3;
    int l15 = (e >> 5) & 15;
    int ks  = (e >> 9) & 7;
    int og  = (e >> 12) & 15;
    int k   = e >> 16;
    int o = og * 16 + l15;
    int c = ks * 32 + l4 * 8 + j;
    Bt[e] = f2bf(w[(o * C_ + c) * 9 + k]);
}

// ---------------- K3: fused offsets + implicit GEMM deformable conv ------------------
// 512 blocks x 512 threads. Block = full row (64 pos) x 128 outs (N half).
// Prologue: compute this row's 64 (ox,oy) in-register (8 threads/pos, shfl reductions).
// Main loop: per-tap gather->LDS (pk-f32 lerp) + MFMA, double-buffered.
__launch_bounds__(512, 4)
__global__ void k_main(const unsigned short* __restrict__ xT,
                       const float* __restrict__ dwc_w,
                       const float* __restrict__ ln_w,
                       const float* __restrict__ ln_b,
                       const float* __restrict__ fcd_w,
                       const float* __restrict__ fca_w,
                       const unsigned short* __restrict__ Bt,
                       const float* __restrict__ bias,
                       float* __restrict__ out)
{
    __shared__ __align__(16) unsigned char smem[65536];  // wsm 9KB -> A dbuf 2x32KB -> epi

    int tid = threadIdx.x;
    int bi = blockIdx.x;
    int g = ((bi & 7) << 6) | (bi >> 3);   // XCD-chunked
    int tile = g >> 1;                     // 0..255 : (b, y) row
    int n0g = g & 1;                       // N half
    int b = tile >> 6;
    int y = tile & 63;

    int lane = tid & 63, wid = tid >> 6;
    int l15 = lane & 15, l4 = lane >> 4;

    int gpos = tid >> 3;                         // 0..63 : position (x coordinate)
    int csub = tid & 7;                          // 8-thread channel split
    int ch0  = csub << 5;                        // 32 channels per thread (prologue)
    unsigned csub16 = (unsigned)csub << 4;       // 16B chunk (gather)
    const unsigned short* xb = xT + (size_t)b * HW_ * C_;
    const char* xbB = (const char*)xb;

    // ======== stage dwc_w transposed: wsm[j][c] ========
    float* wsm = (float*)smem;
    for (int i = tid; i < 2304; i += 512) {
        int c = i / 9, j = i - c * 9;
        wsm[j * 256 + c] = dwc_w[i];
    }
    __syncthreads();

    // ======== prologue: offsets for this row's 64 positions ========
    float ox, oy;
    {
        f32x2 acc2[16];
#pragma unroll
        for (int i = 0; i < 16; ++i) { acc2[i].x = 0.f; acc2[i].y = 0.f; }
#pragma unroll
        for (int j = 0; j < 9; ++j) {
            int gy = y + j / 3 - 1, gx = gpos + j % 3 - 1;
            if (gy >= 0 && gy < H_ && gx >= 0 && gx < W_) {
                const unsigned short* p = xb + (size_t)((gy << 6) + gx) * 256 + ch0;
                const float* wrow = wsm + j * 256 + ch0;
#pragma unroll
                for (int cc = 0; cc < 4; ++cc) {
                    short8 r = *(const short8*)(p + cc * 8);
                    f32x4 wa = *(const f32x4*)(wrow + cc * 8);
                    f32x4 wb2 = *(const f32x4*)(wrow + cc * 8 + 4);
                    f32x2 wp0; wp0.x = wa.x; wp0.y = wa.y;
                    f32x2 wp1; wp1.x = wa.z; wp1.y = wa.w;
                    f32x2 wp2; wp2.x = wb2.x; wp2.y = wb2.y;
                    f32x2 wp3; wp3.x = wb2.z; wp3.y = wb2.w;
                    acc2[cc*4+0] = pk_fma(unpack_bf2(((unsigned*)&r)[0]), wp0, acc2[cc*4+0]);
                    acc2[cc*4+1] = pk_fma(unpack_bf2(((unsigned*)&r)[1]), wp1, acc2[cc*4+1]);
                    acc2[cc*4+2] = pk_fma(unpack_bf2(((unsigned*)&r)[2]), wp2, acc2[cc*4+2]);
                    acc2[cc*4+3] = pk_fma(unpack_bf2(((unsigned*)&r)[3]), wp3, acc2[cc*4+3]);
                }
            }
        }
        f32x2 sum2, sq2;
        sum2.x = 0.f; sum2.y = 0.f; sq2.x = 0.f; sq2.y = 0.f;
#pragma unroll
        for (int i = 0; i < 16; ++i) {
            sum2 = pk_add(sum2, acc2[i]);
            sq2  = pk_fma(acc2[i], acc2[i], sq2);
        }
        float s1 = sum2.x + sum2.y, s2 = sq2.x + sq2.y;
#pragma unroll
        for (int m = 1; m <= 4; m <<= 1) {
            s1 += __shfl_xor(s1, m);
            s2 += __shfl_xor(s2, m);
        }
        float mu  = s1 * (1.f / 256.f);
        float var = s2 * (1.f / 256.f) - mu * mu;
        float rs  = rsqrtf(var + 1e-5f);
        float d1 = 0.f, d2 = 0.f;
#pragma unroll
        for (int cc = 0; cc < 4; ++cc) {
            f32x4 lwa = *(const f32x4*)(ln_w  + ch0 + cc * 8);
            f32x4 lwb = *(const f32x4*)(ln_w  + ch0 + cc * 8 + 4);
            f32x4 lba = *(const f32x4*)(ln_b  + ch0 + cc * 8);
            f32x4 lbb = *(const f32x4*)(ln_b  + ch0 + cc * 8 + 4);
            f32x4 fda = *(const f32x4*)(fcd_w + ch0 + cc * 8);
            f32x4 fdb = *(const f32x4*)(fcd_w + ch0 + cc * 8 + 4);
            f32x4 faa = *(const f32x4*)(fca_w + ch0 + cc * 8);
            f32x4 fab = *(const f32x4*)(fca_w + ch0 + cc * 8 + 4);
#pragma unroll
            for (int i = 0; i < 8; ++i) {
                float av = (i & 1) ? acc2[cc*4 + (i >> 1)].y : acc2[cc*4 + (i >> 1)].x;
                float lw = (i < 4) ? lwa[i] : lwb[i - 4];
                float lb = (i < 4) ? lba[i] : lbb[i - 4];
                float fd = (i < 4) ? fda[i] : fdb[i - 4];
                float fa = (i < 4) ? faa[i] : fab[i - 4];
                float hn = (av - mu) * rs * lw + lb;
                hn = fmaxf(hn, 0.f);
                d1 = fmaf(hn, fd, d1);
                d2 = fmaf(hn, fa, d2);
            }
        }
#pragma unroll
        for (int m = 1; m <= 4; m <<= 1) {
            d1 += __shfl_xor(d1, m);
            d2 += __shfl_xor(d2, m);
        }
        float r0 = fmaxf(d1, 0.f);
        float theta = d2 / (1.f + fabsf(d2)) * 0.017453292519943295f;
        ox = r0 * cosf(theta);
        oy = r0 * sinf(theta);
    }
    __syncthreads();   // wsm reads done; smem can be reused as A buffers

    f32x4 acc[4];
#pragma unroll
    for (int m = 0; m < 4; ++m) {
        acc[m].x = 0.f; acc[m].y = 0.f; acc[m].z = 0.f; acc[m].w = 0.f;
    }

    const unsigned short* bwave = Bt + (unsigned)(n0g * 8 + wid) * 4096u
                                     + (unsigned)(l15 * 32 + l4 * 8);
    unsigned rowb = (unsigned)gpos * 512u;
    unsigned swzoff = (csub16 >> 4 ^ ((unsigned)gpos & 7u)) << 4;

#define GADDR(k)                                                                  \
        int ky = (k) / 3, kx = (k) - ky * 3;                                      \
        float dyv = ((k) <= 4) ? ox : oy;                                         \
        float dxv = ((k) <= 3) ? ox : oy;                                         \
        float py = (float)(y - 1 + ky) + dyv;                                     \
        float px = (float)(gpos - 1 + kx) + dxv;                                  \
        float y0f = floorf(py), x0f = floorf(px);                                 \
        int y0 = (int)y0f, x0 = (int)x0f;                                         \
        int y1 = y0 + 1, x1 = x0 + 1;                                             \
        float wy1 = py - y0f, wy0 = 1.f - wy1;                                    \
        float wx1 = px - x0f, wx0 = 1.f - wx1;                                    \
        float vy0 = (y0 >= 0 && y0 < H_) ? 1.f : 0.f;                             \
        float vy1 = (y1 >= 0 && y1 < H_) ? 1.f : 0.f;                             \
        float vx0 = (x0 >= 0 && x0 < W_) ? 1.f : 0.f;                             \
        float vx1 = (x1 >= 0 && x1 < W_) ? 1.f : 0.f;                             \
        w00 = wy0 * wx0 * vy0 * vx0; w01 = wy0 * wx1 * vy0 * vx1;                 \
        w10 = wy1 * wx0 * vy1 * vx0; w11 = wy1 * wx1 * vy1 * vx1;                 \
        int y0c = min(max(y0, 0), H_ - 1), y1c = min(max(y1, 0), H_ - 1);         \
        int x0c = min(max(x0, 0), W_ - 1), x1c = min(max(x1, 0), W_ - 1);         \
        o00 = (unsigned)((y0c << 6) + x0c) * 512u + csub16;                       \
        o01 = (unsigned)((y0c << 6) + x1c) * 512u + csub16;                       \
        o10 = (unsigned)((y1c << 6) + x0c) * 512u + csub16;                       \
        o11 = (unsigned)((y1c << 6) + x1c) * 512u + csub16;

#define GATHER_TAP(k, buf)                                                        \
    {   unsigned o00, o01, o10, o11;                                              \
        float w00, w01, w10, w11;                                                 \
        GADDR(k);                                                                 \
        f32x2 W00, W01, W10, W11;                                                 \
        W00.x = w00; W00.y = w00; W01.x = w01; W01.y = w01;                       \
        W10.x = w10; W10.y = w10; W11.x = w11; W11.y = w11;                       \
        unsigned wb = (unsigned)(buf) * 32768u + rowb + swzoff;                   \
        _Pragma("unroll")                                                         \
        for (int cq = 0; cq < 4; ++cq) {                                          \
            short8 r00 = *(const short8*)(xbB + o00 + cq * 128);                  \
            short8 r01 = *(const short8*)(xbB + o01 + cq * 128);                  \
            short8 r10 = *(const short8*)(xbB + o10 + cq * 128);                  \
            short8 r11 = *(const short8*)(xbB + o11 + cq * 128);                  \
            uint4 pkv;                                                            \
            _Pragma("unroll")                                                     \
            for (int dw = 0; dw < 4; ++dw) {                                      \
                f32x2 a2 = pk_mul(unpack_bf2(((unsigned*)&r00)[dw]), W00);        \
                a2 = pk_fma(unpack_bf2(((unsigned*)&r01)[dw]), W01, a2);          \
                a2 = pk_fma(unpack_bf2(((unsigned*)&r10)[dw]), W10, a2);          \
                a2 = pk_fma(unpack_bf2(((unsigned*)&r11)[dw]), W11, a2);          \
                ((unsigned*)&pkv)[dw] = cvtpk(a2.x, a2.y);                        \
            }                                                                     \
            *(uint4*)(smem + wb + cq * 128) = pkv;                                \
        }                                                                         \
    }

    // ---- prologue gather: tap 0 into buf0 ----
    GATHER_TAP(0, 0);
    __syncthreads();

#pragma unroll
    for (int k = 0; k < 9; ++k) {
        int t = k & 1;
        // ---- MFMA phase on buf t, tap k ----
        {
            const unsigned short* bk = bwave + (unsigned)k * 65536u;
            unsigned abase = (unsigned)t * 32768u;
#pragma unroll
            for (int ks = 0; ks < 8; ++ks) {
                short8 bf = *(const short8*)(bk + ks * 512);
                unsigned coff = (unsigned)(ks * 64 + (l4 << 4)) ^ (((unsigned)l15 & 7u) << 4);
#pragma unroll
                for (int mf = 0; mf < 4; ++mf) {
                    short8 a = *(const short8*)(smem + abase +
                                 (unsigned)(mf * 16 + l15) * 512u + coff);
                    acc[mf] = __builtin_amdgcn_mfma_f32_16x16x32_bf16(a, bf, acc[mf], 0, 0, 0);
                }
            }
        }
        // ---- gather next tap into buf t^1 (overlaps MFMA via scheduler) ----
        if (k < 8) {
            GATHER_TAP(k + 1, t ^ 1);
        }
        __syncthreads();
    }

    // ---- epilogue: LDS transpose (stride 133) then coalesced NCHW stores ----
    float* epi = (float*)smem;
#pragma unroll
    for (int mf = 0; mf < 4; ++mf)
#pragma unroll
        for (int i = 0; i < 4; ++i) {
            int row = mf * 16 + l4 * 4 + i;      // position 0..63
            int col = wid * 16 + l15;            // local out 0..127
            epi[row * 133 + col] = acc[mf][i];
        }
    __syncthreads();
    int o  = tid >> 2;                 // 0..127
    int wq = (tid & 3) << 4;           // 0,16,32,48
    float bv = bias[n0g * 128 + o];
    float* orow = out + (size_t)(((b * CO_ + n0g * 128 + o) * H_ + y) * W_) + wq;
#pragma unroll
    for (int j = 0; j < 16; j += 4) {
        f32x4 v;
        v.x = epi[(wq + j + 0) * 133 + o] + bv;
        v.y = epi[(wq + j + 1) * 133 + o] + bv;
        v.z = epi[(wq + j + 2) * 133 + o] + bv;
        v.w = epi[(wq + j + 3) * 133 + o] + bv;
        *(f32x4*)(orow + j) = v;
    }
}

extern "C" void kernel_launch(void* const* d_in, const int* in_sizes, int n_in,
                              void* d_out, int out_size, void* d_ws, size_t ws_size,
                              hipStream_t stream) {
    const float* x      = (const float*)d_in[0];
    const float* dwc_w  = (const float*)d_in[1];
    const float* ln_w   = (const float*)d_in[2];
    const float* ln_b   = (const float*)d_in[3];
    const float* fcd_w  = (const float*)d_in[4];
    const float* fca_w  = (const float*)d_in[5];
    const float* dconv_w= (const float*)d_in[6];
    const float* dconv_b= (const float*)d_in[7];
    float* out = (float*)d_out;

    unsigned char* ws = (unsigned char*)d_ws;
    unsigned short* xT = (unsigned short*)(ws);                 // 8 MB bf16 NHWC
    unsigned short* Bt = (unsigned short*)(ws + 8388608);       // 1.18 MB

    k_transpose<<<1024, 256, 0, stream>>>(x, xT);
    k_packB<<<2304, 256, 0, stream>>>(dconv_w, Bt);
    k_main<<<512, 512, 0, stream>>>(xT, dwc_w, ln_w, ln_b, fcd_w, fca_w, Bt, dconv_b, out);
}

// Round 9
// 78.077 us; speedup vs baseline: 2.4296x; 1.0500x over previous
//
#include <hip/hip_runtime.h>
#include <hip/hip_bf16.h>

#define B_   4
#define C_   256
#define CO_  256
#define H_   64
#define W_   64
#define HW_  4096

typedef __attribute__((ext_vector_type(8))) short short8;
typedef __attribute__((ext_vector_type(4))) float f32x4;
typedef __attribute__((ext_vector_type(2))) float f32x2;

static __device__ __forceinline__ unsigned short f2bf(float f) {
    unsigned u = __builtin_bit_cast(unsigned, f);
    unsigned r = (u + 0x7fffu + ((u >> 16) & 1u)) >> 16;
    return (unsigned short)r;
}
static __device__ __forceinline__ f32x2 pk_mul(f32x2 a, f32x2 b) {
    f32x2 d; asm("v_pk_mul_f32 %0, %1, %2" : "=v"(d) : "v"(a), "v"(b)); return d;
}
static __device__ __forceinline__ f32x2 pk_fma(f32x2 a, f32x2 b, f32x2 c) {
    f32x2 d; asm("v_pk_fma_f32 %0, %1, %2, %3" : "=v"(d) : "v"(a), "v"(b), "v"(c)); return d;
}
static __device__ __forceinline__ f32x2 pk_add(f32x2 a, f32x2 b) {
    f32x2 d; asm("v_pk_add_f32 %0, %1, %2" : "=v"(d) : "v"(a), "v"(b)); return d;
}
static __device__ __forceinline__ unsigned cvtpk(float a, float b) {
    unsigned r; asm("v_cvt_pk_bf16_f32 %0, %1, %2" : "=v"(r) : "v"(a), "v"(b)); return r;
}
static __device__ __forceinline__ f32x2 unpack_bf2(unsigned d) {
    f32x2 v;
    v.x = __builtin_bit_cast(float, d << 16);
    v.y = __builtin_bit_cast(float, d & 0xffff0000u);
    return v;
}

// ---------------- K1: NCHW f32 -> NHWC bf16 transpose (vectorized) -------------------
__global__ void k_transpose(const float* __restrict__ x, unsigned short* __restrict__ xT)
{
    __shared__ float t[32][132];
    int bid = blockIdx.x;            // 1024 = b(4) * hwT(128) * cT(2)
    int b   = bid >> 8;
    int rem = bid & 255;
    int hwT = rem >> 1, cT = rem & 1;
    int hw0 = hwT * 32, c0 = cT * 128;
    int tid = threadIdx.x;
    const float* src = x + (size_t)b * C_ * HW_;
    {
        int hw4 = (tid & 7) << 2;
        int cr  = tid >> 3;
#pragma unroll
        for (int it = 0; it < 4; ++it) {
            int c = cr + it * 32;
            f32x4 v = *(const f32x4*)(src + (size_t)(c0 + c) * HW_ + hw0 + hw4);
            t[hw4 + 0][c] = v.x;
            t[hw4 + 1][c] = v.y;
            t[hw4 + 2][c] = v.z;
            t[hw4 + 3][c] = v.w;
        }
    }
    __syncthreads();
    {
        int c8  = (tid & 15) << 3;
        int hwr = tid >> 4;
        unsigned short* dst = xT + (size_t)(((b << 12) + hw0) * 256) + c0 + c8;
#pragma unroll
        for (int it = 0; it < 2; ++it) {
            int hw = hwr + it * 16;
            f32x4 va = *(const f32x4*)&t[hw][c8];
            f32x4 vb = *(const f32x4*)&t[hw][c8 + 4];
            uint4 u;
            u.x = cvtpk(va.x, va.y);
            u.y = cvtpk(va.z, va.w);
            u.z = cvtpk(vb.x, vb.y);
            u.w = cvtpk(vb.z, vb.w);
            *(uint4*)(dst + (size_t)hw * 256) = u;
        }
    }
}

// ---------------- K2: pack dconv_w -> fragment-ordered Bt; transpose dwc_w -----------
// Bt index = ((((k*16+og)*8+ks)*16+l15)*4+l4)*8 + j ; o = og*16+l15 ; c = ks*32+l4*8+j
__global__ void k_packB(const float* __restrict__ w, unsigned short* __restrict__ Bt,
                        const float* __restrict__ dwc_w, float* __restrict__ dwcT)
{
    int bid = blockIdx.x;
    int tid = threadIdx.x;
    if (bid < 9) dwcT[bid * 256 + tid] = dwc_w[tid * 9 + bid];
    int e = bid * 256 + tid;
    int j   = e & 7;
    int l4  = (e >> 3) & 3;
    int l15 = (e >> 5) & 15;
    int ks  = (e >> 9) & 7;
    int og  = (e >> 12) & 15;
    int k   = e >> 16;
    int o = og * 16 + l15;
    int c = ks * 32 + l4 * 8 + j;
    Bt[e] = f2bf(w[(o * C_ + c) * 9 + k]);
}

// ---------------- K3: fused offsets + implicit GEMM deformable conv ------------------
// 512 blocks x 512 threads. Block = 32 positions x full N=256 (offsets computed ONCE).
// Wave = 32 pos (2 M-frags) x 32 outs (2 N-frags). LDS 33KB: dbuf 2x16KB / epi 32.9KB.
__launch_bounds__(512, 4)
__global__ void k_main(const unsigned short* __restrict__ xT,
                       const float* __restrict__ dwcT,
                       const float* __restrict__ ln_w,
                       const float* __restrict__ ln_b,
                       const float* __restrict__ fcd_w,
                       const float* __restrict__ fca_w,
                       const unsigned short* __restrict__ Bt,
                       const float* __restrict__ bias,
                       float* __restrict__ out)
{
    __shared__ __align__(16) unsigned char smem[33024];

    int tid = threadIdx.x;
    int bi = blockIdx.x;
    int g = ((bi & 7) << 6) | (bi >> 3);   // XCD-chunked
    int p0 = g << 5;
    int b = p0 >> 12;
    int y = (p0 >> 6) & 63;
    int xh = p0 & 63;                      // 0 or 32

    int lane = tid & 63, wid = tid >> 6;
    int l15 = lane & 15, l4 = lane >> 4;

    int gpos = tid >> 4;                   // 0..31 position
    int csub = tid & 15;                   // 16-way channel split
    const unsigned short* xb = xT + (size_t)b * HW_ * C_;
    const char* xbB = (const char*)xb;

    // ======== prologue: offsets for this block's 32 positions (once) ========
    float ox, oy;
    {
        int ch0 = csub << 4;               // 16 channels per thread
        f32x2 acc2[8];
#pragma unroll
        for (int i = 0; i < 8; ++i) { acc2[i].x = 0.f; acc2[i].y = 0.f; }
#pragma unroll
        for (int j = 0; j < 9; ++j) {
            int gy = y + j / 3 - 1, gx = xh + gpos + j % 3 - 1;
            if (gy >= 0 && gy < H_ && gx >= 0 && gx < W_) {
                const unsigned short* p = xb + (size_t)((gy << 6) + gx) * 256 + ch0;
                short8 rlo = *(const short8*)(p);
                short8 rhi = *(const short8*)(p + 8);
                const float* wrow = dwcT + j * 256 + ch0;
#pragma unroll
                for (int q = 0; q < 4; ++q) {
                    f32x4 wv = *(const f32x4*)(wrow + q * 4);
                    f32x2 w01v; w01v.x = wv.x; w01v.y = wv.y;
                    f32x2 w23v; w23v.x = wv.z; w23v.y = wv.w;
                    unsigned lo = (q < 2) ? ((unsigned*)&rlo)[q * 2] : ((unsigned*)&rhi)[(q - 2) * 2];
                    unsigned hi = (q < 2) ? ((unsigned*)&rlo)[q * 2 + 1] : ((unsigned*)&rhi)[(q - 2) * 2 + 1];
                    acc2[q * 2 + 0] = pk_fma(unpack_bf2(lo), w01v, acc2[q * 2 + 0]);
                    acc2[q * 2 + 1] = pk_fma(unpack_bf2(hi), w23v, acc2[q * 2 + 1]);
                }
            }
        }
        f32x2 sum2, sq2;
        sum2.x = 0.f; sum2.y = 0.f; sq2.x = 0.f; sq2.y = 0.f;
#pragma unroll
        for (int i = 0; i < 8; ++i) {
            sum2 = pk_add(sum2, acc2[i]);
            sq2  = pk_fma(acc2[i], acc2[i], sq2);
        }
        float s1 = sum2.x + sum2.y, s2 = sq2.x + sq2.y;
#pragma unroll
        for (int m = 1; m <= 8; m <<= 1) {
            s1 += __shfl_xor(s1, m);
            s2 += __shfl_xor(s2, m);
        }
        float mu  = s1 * (1.f / 256.f);
        float var = s2 * (1.f / 256.f) - mu * mu;
        float rs  = rsqrtf(var + 1e-5f);
        float d1 = 0.f, d2 = 0.f;
#pragma unroll
        for (int q = 0; q < 4; ++q) {
            f32x4 lwv = *(const f32x4*)(ln_w  + ch0 + q * 4);
            f32x4 lbv = *(const f32x4*)(ln_b  + ch0 + q * 4);
            f32x4 fdv = *(const f32x4*)(fcd_w + ch0 + q * 4);
            f32x4 fav = *(const f32x4*)(fca_w + ch0 + q * 4);
#pragma unroll
            for (int i = 0; i < 4; ++i) {
                float av = (i & 1) ? acc2[q * 2 + (i >> 1)].y : acc2[q * 2 + (i >> 1)].x;
                float hn = (av - mu) * rs * lwv[i] + lbv[i];
                hn = fmaxf(hn, 0.f);
                d1 = fmaf(hn, fdv[i], d1);
                d2 = fmaf(hn, fav[i], d2);
            }
        }
#pragma unroll
        for (int m = 1; m <= 8; m <<= 1) {
            d1 += __shfl_xor(d1, m);
            d2 += __shfl_xor(d2, m);
        }
        float r0 = fmaxf(d1, 0.f);
        float theta = d2 / (1.f + fabsf(d2)) * 0.017453292519943295f;
        ox = r0 * cosf(theta);
        oy = r0 * sinf(theta);
    }

    f32x4 acc[2][2];
#pragma unroll
    for (int m = 0; m < 2; ++m)
#pragma unroll
        for (int n = 0; n < 2; ++n) {
            acc[m][n].x = 0.f; acc[m][n].y = 0.f; acc[m][n].z = 0.f; acc[m][n].w = 0.f;
        }

    const unsigned short* bwave = Bt + (unsigned)(wid * 2) * 4096u
                                     + (unsigned)(l15 * 32 + l4 * 8);
    unsigned rowb = (unsigned)gpos * 512u;
    unsigned csub16 = (unsigned)csub << 4;
    unsigned swzcol = csub16 ^ (((unsigned)gpos & 7u) << 4);   // bits 4-7 ^ bits 4-6

#define GADDR(k)                                                                  \
        int ky = (k) / 3, kx = (k) - ky * 3;                                      \
        float dyv = ((k) <= 4) ? ox : oy;                                         \
        float dxv = ((k) <= 3) ? ox : oy;                                         \
        float py = (float)(y - 1 + ky) + dyv;                                     \
        float px = (float)(xh + gpos - 1 + kx) + dxv;                             \
        float y0f = floorf(py), x0f = floorf(px);                                 \
        int y0 = (int)y0f, x0 = (int)x0f;                                         \
        int y1 = y0 + 1, x1 = x0 + 1;                                             \
        float wy1 = py - y0f, wy0 = 1.f - wy1;                                    \
        float wx1 = px - x0f, wx0 = 1.f - wx1;                                    \
        float vy0 = (y0 >= 0 && y0 < H_) ? 1.f : 0.f;                             \
        float vy1 = (y1 >= 0 && y1 < H_) ? 1.f : 0.f;                             \
        float vx0 = (x0 >= 0 && x0 < W_) ? 1.f : 0.f;                             \
        float vx1 = (x1 >= 0 && x1 < W_) ? 1.f : 0.f;                             \
        w00 = wy0 * wx0 * vy0 * vx0; w01 = wy0 * wx1 * vy0 * vx1;                 \
        w10 = wy1 * wx0 * vy1 * vx0; w11 = wy1 * wx1 * vy1 * vx1;                 \
        int y0c = min(max(y0, 0), H_ - 1), y1c = min(max(y1, 0), H_ - 1);         \
        int x0c = min(max(x0, 0), W_ - 1), x1c = min(max(x1, 0), W_ - 1);         \
        o00 = (unsigned)((y0c << 6) + x0c) * 512u + csub16;                       \
        o01 = (unsigned)((y0c << 6) + x1c) * 512u + csub16;                       \
        o10 = (unsigned)((y1c << 6) + x0c) * 512u + csub16;                       \
        o11 = (unsigned)((y1c << 6) + x1c) * 512u + csub16;

#define GATHER_TAP(k, buf)                                                        \
    {   unsigned o00, o01, o10, o11;                                              \
        float w00, w01, w10, w11;                                                 \
        GADDR(k);                                                                 \
        f32x2 W00, W01, W10, W11;                                                 \
        W00.x = w00; W00.y = w00; W01.x = w01; W01.y = w01;                       \
        W10.x = w10; W10.y = w10; W11.x = w11; W11.y = w11;                       \
        unsigned wb = (unsigned)(buf) * 16384u + rowb + swzcol;                   \
        _Pragma("unroll")                                                         \
        for (int cq = 0; cq < 2; ++cq) {                                          \
            short8 r00 = *(const short8*)(xbB + o00 + cq * 256);                  \
            short8 r01 = *(const short8*)(xbB + o01 + cq * 256);                  \
            short8 r10 = *(const short8*)(xbB + o10 + cq * 256);                  \
            short8 r11 = *(const short8*)(xbB + o11 + cq * 256);                  \
            uint4 pkv;                                                            \
            _Pragma("unroll")                                                     \
            for (int dw = 0; dw < 4; ++dw) {                                      \
                f32x2 a2 = pk_mul(unpack_bf2(((unsigned*)&r00)[dw]), W00);        \
                a2 = pk_fma(unpack_bf2(((unsigned*)&r01)[dw]), W01, a2);          \
                a2 = pk_fma(unpack_bf2(((unsigned*)&r10)[dw]), W10, a2);          \
                a2 = pk_fma(unpack_bf2(((unsigned*)&r11)[dw]), W11, a2);          \
                ((unsigned*)&pkv)[dw] = cvtpk(a2.x, a2.y);                        \
            }                                                                     \
            *(uint4*)(smem + wb + cq * 256) = pkv;                                \
        }                                                                         \
    }

    // ---- prologue gather: tap 0 into buf0 ----
    GATHER_TAP(0, 0);
    __syncthreads();

#pragma unroll
    for (int k = 0; k < 9; ++k) {
        int t = k & 1;
        // ---- MFMA phase on buf t, tap k ----
        {
            const unsigned short* bk = bwave + (unsigned)k * 65536u;
            unsigned abase = (unsigned)t * 16384u;
#pragma unroll
            for (int ks = 0; ks < 8; ++ks) {
                short8 bf0 = *(const short8*)(bk + ks * 512);
                short8 bf1 = *(const short8*)(bk + 4096 + ks * 512);
                unsigned coff = (unsigned)(ks * 64 + (l4 << 4)) ^ (((unsigned)l15 & 7u) << 4);
                short8 a0 = *(const short8*)(smem + abase + (unsigned)l15 * 512u + coff);
                short8 a1 = *(const short8*)(smem + abase + (unsigned)(16 + l15) * 512u + coff);
                acc[0][0] = __builtin_amdgcn_mfma_f32_16x16x32_bf16(a0, bf0, acc[0][0], 0, 0, 0);
                acc[0][1] = __builtin_amdgcn_mfma_f32_16x16x32_bf16(a0, bf1, acc[0][1], 0, 0, 0);
                acc[1][0] = __builtin_amdgcn_mfma_f32_16x16x32_bf16(a1, bf0, acc[1][0], 0, 0, 0);
                acc[1][1] = __builtin_amdgcn_mfma_f32_16x16x32_bf16(a1, bf1, acc[1][1], 0, 0, 0);
            }
        }
        // ---- gather next tap into buf t^1 (overlaps MFMA via scheduler) ----
        if (k < 8) {
            GATHER_TAP(k + 1, t ^ 1);
        }
        __syncthreads();
    }

    // ---- epilogue: LDS transpose (stride 257) then coalesced NCHW stores ----
    float* epi = (float*)smem;
#pragma unroll
    for (int m = 0; m < 2; ++m)
#pragma unroll
        for (int n = 0; n < 2; ++n)
#pragma unroll
            for (int i = 0; i < 4; ++i) {
                int row = m * 16 + l4 * 4 + i;          // position 0..31
                int col = wid * 32 + n * 16 + l15;      // out 0..255
                epi[row * 257 + col] = acc[m][n][i];
            }
    __syncthreads();
    int o  = tid >> 1;                 // 0..255
    int wq = (tid & 1) << 4;           // 0 or 16
    float bv = bias[o];
    float* orow = out + (size_t)(((b * CO_ + o) * H_ + y) * W_) + xh + wq;
#pragma unroll
    for (int j = 0; j < 16; j += 4) {
        f32x4 v;
        v.x = epi[(wq + j + 0) * 257 + o] + bv;
        v.y = epi[(wq + j + 1) * 257 + o] + bv;
        v.z = epi[(wq + j + 2) * 257 + o] + bv;
        v.w = epi[(wq + j + 3) * 257 + o] + bv;
        *(f32x4*)(orow + j) = v;
    }
}

extern "C" void kernel_launch(void* const* d_in, const int* in_sizes, int n_in,
                              void* d_out, int out_size, void* d_ws, size_t ws_size,
                              hipStream_t stream) {
    const float* x      = (const float*)d_in[0];
    const float* dwc_w  = (const float*)d_in[1];
    const float* ln_w   = (const float*)d_in[2];
    const float* ln_b   = (const float*)d_in[3];
    const float* fcd_w  = (const float*)d_in[4];
    const float* fca_w  = (const float*)d_in[5];
    const float* dconv_w= (const float*)d_in[6];
    const float* dconv_b= (const float*)d_in[7];
    float* out = (float*)d_out;

    unsigned char* ws = (unsigned char*)d_ws;
    unsigned short* xT = (unsigned short*)(ws);                 // 8 MB bf16 NHWC
    unsigned short* Bt = (unsigned short*)(ws + 8388608);       // 1.18 MB
    float* dwcT        = (float*)(ws + 9568256);                // 9 KB

    k_transpose<<<1024, 256, 0, stream>>>(x, xT);
    k_packB<<<2304, 256, 0, stream>>>(dconv_w, Bt, dwc_w, dwcT);
    k_main<<<512, 512, 0, stream>>>(xT, dwcT, ln_w, ln_b, fcd_w, fca_w, Bt, dconv_b, out);
}

// Round 11
// 76.392 us; speedup vs baseline: 2.4832x; 1.0221x over previous
//
#include <hip/hip_runtime.h>
#include <hip/hip_bf16.h>

#define B_   4
#define C_   256
#define CO_  256
#define H_   64
#define W_   64
#define HW_  4096

typedef __attribute__((ext_vector_type(8))) short short8;
typedef __attribute__((ext_vector_type(4))) float f32x4;
typedef __attribute__((ext_vector_type(2))) float f32x2;

static __device__ __forceinline__ unsigned short f2bf(float f) {
    unsigned u = __builtin_bit_cast(unsigned, f);
    unsigned r = (u + 0x7fffu + ((u >> 16) & 1u)) >> 16;
    return (unsigned short)r;
}
static __device__ __forceinline__ f32x2 pk_mul(f32x2 a, f32x2 b) {
    f32x2 d; asm("v_pk_mul_f32 %0, %1, %2" : "=v"(d) : "v"(a), "v"(b)); return d;
}
static __device__ __forceinline__ f32x2 pk_fma(f32x2 a, f32x2 b, f32x2 c) {
    f32x2 d; asm("v_pk_fma_f32 %0, %1, %2, %3" : "=v"(d) : "v"(a), "v"(b), "v"(c)); return d;
}
static __device__ __forceinline__ f32x2 pk_add(f32x2 a, f32x2 b) {
    f32x2 d; asm("v_pk_add_f32 %0, %1, %2" : "=v"(d) : "v"(a), "v"(b)); return d;
}
static __device__ __forceinline__ unsigned cvtpk(float a, float b) {
    unsigned r; asm("v_cvt_pk_bf16_f32 %0, %1, %2" : "=v"(r) : "v"(a), "v"(b)); return r;
}
static __device__ __forceinline__ f32x2 unpack_bf2(unsigned d) {
    f32x2 v;
    v.x = __builtin_bit_cast(float, d << 16);
    v.y = __builtin_bit_cast(float, d & 0xffff0000u);
    return v;
}

// ---------------- K1: NCHW f32 -> NHWC bf16 transpose (vectorized) -------------------
__global__ void k_transpose(const float* __restrict__ x, unsigned short* __restrict__ xT)
{
    __shared__ float t[32][132];
    int bid = blockIdx.x;            // 1024 = b(4) * hwT(128) * cT(2)
    int b   = bid >> 8;
    int rem = bid & 255;
    int hwT = rem >> 1, cT = rem & 1;
    int hw0 = hwT * 32, c0 = cT * 128;
    int tid = threadIdx.x;
    const float* src = x + (size_t)b * C_ * HW_;
    {
        int hw4 = (tid & 7) << 2;
        int cr  = tid >> 3;
#pragma unroll
        for (int it = 0; it < 4; ++it) {
            int c = cr + it * 32;
            f32x4 v = *(const f32x4*)(src + (size_t)(c0 + c) * HW_ + hw0 + hw4);
            t[hw4 + 0][c] = v.x;
            t[hw4 + 1][c] = v.y;
            t[hw4 + 2][c] = v.z;
            t[hw4 + 3][c] = v.w;
        }
    }
    __syncthreads();
    {
        int c8  = (tid & 15) << 3;
        int hwr = tid >> 4;
        unsigned short* dst = xT + (size_t)(((b << 12) + hw0) * 256) + c0 + c8;
#pragma unroll
        for (int it = 0; it < 2; ++it) {
            int hw = hwr + it * 16;
            f32x4 va = *(const f32x4*)&t[hw][c8];
            f32x4 vb = *(const f32x4*)&t[hw][c8 + 4];
            uint4 u;
            u.x = cvtpk(va.x, va.y);
            u.y = cvtpk(va.z, va.w);
            u.z = cvtpk(vb.x, vb.y);
            u.w = cvtpk(vb.z, vb.w);
            *(uint4*)(dst + (size_t)hw * 256) = u;
        }
    }
}

// ---------------- K2: pack dconv_w -> fragment-ordered Bt; transpose dwc_w -----------
// Bt index = ((((k*16+og)*8+ks)*16+l15)*4+l4)*8 + j ; o = og*16+l15 ; c = ks*32+l4*8+j
__global__ void k_packB(const float* __restrict__ w, unsigned short* __restrict__ Bt,
                        const float* __restrict__ dwc_w, float* __restrict__ dwcT)
{
    int bid = blockIdx.x;
    int tid = threadIdx.x;
    if (bid < 9) dwcT[bid * 256 + tid] = dwc_w[tid * 9 + bid];
    int e = bid * 256 + tid;
    int j   = e & 7;
    int l4  = (e >> 3) & 3;
    int l15 = (e >> 5) & 15;
    int ks  = (e >> 9) & 7;
    int og  = (e >> 12) & 15;
    int k   = e >> 16;
    int o = og * 16 + l15;
    int c = ks * 32 + l4 * 8 + j;
    Bt[e] = f2bf(w[(o * C_ + c) * 9 + k]);
}

// ---------------- K3: offsets — 512 blocks x 512 thr, 16 lanes/position, no LDS ------
__global__ void k_offsets(const unsigned short* __restrict__ xT,
                          const float* __restrict__ dwcT,
                          const float* __restrict__ ln_w,
                          const float* __restrict__ ln_b,
                          const float* __restrict__ fcd_w,
                          const float* __restrict__ fca_w,
                          float* __restrict__ OX, float* __restrict__ OY)
{
    int tid = threadIdx.x;
    int bi = blockIdx.x;
    int g = ((bi & 7) << 6) | (bi >> 3);   // XCD swizzle (matches k_main row ownership)
    int p0 = g << 5;
    int b = p0 >> 12;
    int y = (p0 >> 6) & 63;
    int xh = p0 & 63;
    int gpos = tid >> 4;                   // 0..31
    int csub = tid & 15;
    int ch0 = csub << 4;                   // 16 channels per thread
    const unsigned short* xb = xT + (size_t)b * HW_ * C_;

    f32x2 acc2[8];
#pragma unroll
    for (int i = 0; i < 8; ++i) { acc2[i].x = 0.f; acc2[i].y = 0.f; }
#pragma unroll
    for (int j = 0; j < 9; ++j) {
        int gy = y + j / 3 - 1, gx = xh + gpos + j % 3 - 1;
        if (gy >= 0 && gy < H_ && gx >= 0 && gx < W_) {
            const unsigned short* p = xb + (size_t)((gy << 6) + gx) * 256 + ch0;
            short8 rlo = *(const short8*)(p);
            short8 rhi = *(const short8*)(p + 8);
            const float* wrow = dwcT + j * 256 + ch0;
#pragma unroll
            for (int q = 0; q < 4; ++q) {
                f32x4 wv = *(const f32x4*)(wrow + q * 4);
                f32x2 w01v; w01v.x = wv.x; w01v.y = wv.y;
                f32x2 w23v; w23v.x = wv.z; w23v.y = wv.w;
                unsigned lo = (q < 2) ? ((unsigned*)&rlo)[q * 2] : ((unsigned*)&rhi)[(q - 2) * 2];
                unsigned hi = (q < 2) ? ((unsigned*)&rlo)[q * 2 + 1] : ((unsigned*)&rhi)[(q - 2) * 2 + 1];
                acc2[q * 2 + 0] = pk_fma(unpack_bf2(lo), w01v, acc2[q * 2 + 0]);
                acc2[q * 2 + 1] = pk_fma(unpack_bf2(hi), w23v, acc2[q * 2 + 1]);
            }
        }
    }
    f32x2 sum2, sq2;
    sum2.x = 0.f; sum2.y = 0.f; sq2.x = 0.f; sq2.y = 0.f;
#pragma unroll
    for (int i = 0; i < 8; ++i) {
        sum2 = pk_add(sum2, acc2[i]);
        sq2  = pk_fma(acc2[i], acc2[i], sq2);
    }
    float s1 = sum2.x + sum2.y, s2 = sq2.x + sq2.y;
#pragma unroll
    for (int m = 1; m <= 8; m <<= 1) {
        s1 += __shfl_xor(s1, m);
        s2 += __shfl_xor(s2, m);
    }
    float mu  = s1 * (1.f / 256.f);
    float var = s2 * (1.f / 256.f) - mu * mu;
    float rs  = rsqrtf(var + 1e-5f);
    float d1 = 0.f, d2 = 0.f;
#pragma unroll
    for (int q = 0; q < 4; ++q) {
        f32x4 lwv = *(const f32x4*)(ln_w  + ch0 + q * 4);
        f32x4 lbv = *(const f32x4*)(ln_b  + ch0 + q * 4);
        f32x4 fdv = *(const f32x4*)(fcd_w + ch0 + q * 4);
        f32x4 fav = *(const f32x4*)(fca_w + ch0 + q * 4);
#pragma unroll
        for (int i = 0; i < 4; ++i) {
            float av = (i & 1) ? acc2[q * 2 + (i >> 1)].y : acc2[q * 2 + (i >> 1)].x;
            float hn = (av - mu) * rs * lwv[i] + lbv[i];
            hn = fmaxf(hn, 0.f);
            d1 = fmaf(hn, fdv[i], d1);
            d2 = fmaf(hn, fav[i], d2);
        }
    }
#pragma unroll
    for (int m = 1; m <= 8; m <<= 1) {
        d1 += __shfl_xor(d1, m);
        d2 += __shfl_xor(d2, m);
    }
    if (csub == 0) {
        float r0 = fmaxf(d1, 0.f);
        float theta = d2 / (1.f + fabsf(d2)) * 0.017453292519943295f;
        int pos = p0 + gpos;
        OX[pos] = r0 * cosf(theta);
        OY[pos] = r0 * sinf(theta);
    }
}

// ---------------- K4: implicit GEMM deformable conv (R7 structure + pk lerp) ---------
// 512 blocks x 512 threads. Block = full row (64 pos) x 128 outs (N half).
// Wave = 64 pos (4 M-frags) x 16 outs: each B frag feeds 4 MFMAs; B 1KB/instr;
// gather per-instr contiguous 128B/position; LDS swizzled; pk-f32 lerp.
__launch_bounds__(512, 4)
__global__ void k_main(const unsigned short* __restrict__ xT,
                       const float* __restrict__ OX, const float* __restrict__ OY,
                       const unsigned short* __restrict__ Bt,
                       const float* __restrict__ bias,
                       float* __restrict__ out)
{
    __shared__ __align__(16) unsigned char smem[65536];  // A dbuf 2x32KB / epilogue 34KB

    int tid = threadIdx.x;
    int bi = blockIdx.x;
    int g = ((bi & 7) << 6) | (bi >> 3);   // XCD-chunked; pair (2t,2t+1) = same row
    int tile = g >> 1;                     // 0..255 : (b, y) row
    int n0g = g & 1;                       // N half
    int b = tile >> 6;
    int y = tile & 63;

    int lane = tid & 63, wid = tid >> 6;
    int l15 = lane & 15, l4 = lane >> 4;

    f32x4 acc[4];
#pragma unroll
    for (int m = 0; m < 4; ++m) {
        acc[m].x = 0.f; acc[m].y = 0.f; acc[m].z = 0.f; acc[m].w = 0.f;
    }

    int gpos = tid >> 3;                   // 0..63 : position (x coordinate)
    unsigned csub16 = ((unsigned)tid & 7u) << 4;   // 16B chunk within 128B quarter
    const char* xbB = (const char*)(xT + (size_t)b * HW_ * C_);
    const unsigned short* bwave = Bt + (unsigned)(n0g * 8 + wid) * 4096u
                                     + (unsigned)(l15 * 32 + l4 * 8);
    unsigned rowb = (unsigned)gpos * 512u;
    unsigned swzcol = csub16 ^ (((unsigned)gpos & 7u) << 4);
    float ox = OX[(tile << 6) + gpos], oy = OY[(tile << 6) + gpos];

#define GADDR(k)                                                                  \
        int ky = (k) / 3, kx = (k) - ky * 3;                                      \
        float dyv = ((k) <= 4) ? ox : oy;                                         \
        float dxv = ((k) <= 3) ? ox : oy;                                         \
        float py = (float)(y - 1 + ky) + dyv;                                     \
        float px = (float)(gpos - 1 + kx) + dxv;                                  \
        float y0f = floorf(py), x0f = floorf(px);                                 \
        int y0 = (int)y0f, x0 = (int)x0f;                                         \
        int y1 = y0 + 1, x1 = x0 + 1;                                             \
        float wy1 = py - y0f, wy0 = 1.f - wy1;                                    \
        float wx1 = px - x0f, wx0 = 1.f - wx1;                                    \
        float vy0 = (y0 >= 0 && y0 < H_) ? 1.f : 0.f;                             \
        float vy1 = (y1 >= 0 && y1 < H_) ? 1.f : 0.f;                             \
        float vx0 = (x0 >= 0 && x0 < W_) ? 1.f : 0.f;                             \
        float vx1 = (x1 >= 0 && x1 < W_) ? 1.f : 0.f;                             \
        w00 = wy0 * wx0 * vy0 * vx0; w01 = wy0 * wx1 * vy0 * vx1;                 \
        w10 = wy1 * wx0 * vy1 * vx0; w11 = wy1 * wx1 * vy1 * vx1;                 \
        int y0c = min(max(y0, 0), H_ - 1), y1c = min(max(y1, 0), H_ - 1);         \
        int x0c = min(max(x0, 0), W_ - 1), x1c = min(max(x1, 0), W_ - 1);         \
        o00 = (unsigned)((y0c << 6) + x0c) * 512u + csub16;                       \
        o01 = (unsigned)((y0c << 6) + x1c) * 512u + csub16;                       \
        o10 = (unsigned)((y1c << 6) + x0c) * 512u + csub16;                       \
        o11 = (unsigned)((y1c << 6) + x1c) * 512u + csub16;

#define GATHER_TAP(k, buf)                                                        \
    {   unsigned o00, o01, o10, o11;                                              \
        float w00, w01, w10, w11;                                                 \
        GADDR(k);                                                                 \
        f32x2 W00, W01, W10, W11;                                                 \
        W00.x = w00; W00.y = w00; W01.x = w01; W01.y = w01;                       \
        W10.x = w10; W10.y = w10; W11.x = w11; W11.y = w11;                       \
        unsigned wb = (unsigned)(buf) * 32768u + rowb + swzcol;                   \
        _Pragma("unroll")                                                         \
        for (int cq = 0; cq < 4; ++cq) {                                          \
            short8 r00 = *(const short8*)(xbB + o00 + cq * 128);                  \
            short8 r01 = *(const short8*)(xbB + o01 + cq * 128);                  \
            short8 r10 = *(const short8*)(xbB + o10 + cq * 128);                  \
            short8 r11 = *(const short8*)(xbB + o11 + cq * 128);                  \
            uint4 pkv;                                                            \
            _Pragma("unroll")                                                     \
            for (int dw = 0; dw < 4; ++dw) {                                      \
                f32x2 a2 = pk_mul(unpack_bf2(((unsigned*)&r00)[dw]), W00);        \
                a2 = pk_fma(unpack_bf2(((unsigned*)&r01)[dw]), W01, a2);          \
                a2 = pk_fma(unpack_bf2(((unsigned*)&r10)[dw]), W10, a2);          \
                a2 = pk_fma(unpack_bf2(((unsigned*)&r11)[dw]), W11, a2);          \
                ((unsigned*)&pkv)[dw] = cvtpk(a2.x, a2.y);                        \
            }                                                                     \
            *(uint4*)(smem + wb + cq * 128) = pkv;                                \
        }                                                                         \
    }

    // ---- prologue: tap 0 into buf0 ----
    GATHER_TAP(0, 0);
    __syncthreads();

#pragma unroll
    for (int k = 0; k < 9; ++k) {
        int t = k & 1;
        // ---- MFMA phase on buf t, tap k ----
        {
            const unsigned short* bk = bwave + (unsigned)k * 65536u;
            unsigned abase = (unsigned)t * 32768u;
#pragma unroll
            for (int ks = 0; ks < 8; ++ks) {
                short8 bf = *(const short8*)(bk + ks * 512);
                unsigned coff = (unsigned)(ks * 64 + (l4 << 4)) ^ (((unsigned)l15 & 7u) << 4);
#pragma unroll
                for (int mf = 0; mf < 4; ++mf) {
                    short8 a = *(const short8*)(smem + abase +
                                 (unsigned)(mf * 16 + l15) * 512u + coff);
                    acc[mf] = __builtin_amdgcn_mfma_f32_16x16x32_bf16(a, bf, acc[mf], 0, 0, 0);
                }
            }
        }
        // ---- gather next tap into buf t^1 (overlaps MFMA via scheduler) ----
        if (k < 8) {
            GATHER_TAP(k + 1, t ^ 1);
        }
        __syncthreads();
    }

    // ---- epilogue: LDS transpose (stride 133) then coalesced NCHW stores ----
    float* epi = (float*)smem;
#pragma unroll
    for (int mf = 0; mf < 4; ++mf)
#pragma unroll
        for (int i = 0; i < 4; ++i) {
            int row = mf * 16 + l4 * 4 + i;      // position 0..63
            int col = wid * 16 + l15;            // local out 0..127
            epi[row * 133 + col] = acc[mf][i];
        }
    __syncthreads();
    int o  = tid >> 2;                 // 0..127
    int wq = (tid & 3) << 4;           // 0,16,32,48
    float bv = bias[n0g * 128 + o];
    float* orow = out + (size_t)(((b * CO_ + n0g * 128 + o) * H_ + y) * W_) + wq;
#pragma unroll
    for (int j = 0; j < 16; j += 4) {
        f32x4 v;
        v.x = epi[(wq + j + 0) * 133 + o] + bv;
        v.y = epi[(wq + j + 1) * 133 + o] + bv;
        v.z = epi[(wq + j + 2) * 133 + o] + bv;
        v.w = epi[(wq + j + 3) * 133 + o] + bv;
        *(f32x4*)(orow + j) = v;
    }
}

extern "C" void kernel_launch(void* const* d_in, const int* in_sizes, int n_in,
                              void* d_out, int out_size, void* d_ws, size_t ws_size,
                              hipStream_t stream) {
    const float* x      = (const float*)d_in[0];
    const float* dwc_w  = (const float*)d_in[1];
    const float* ln_w   = (const float*)d_in[2];
    const float* ln_b   = (const float*)d_in[3];
    const float* fcd_w  = (const float*)d_in[4];
    const float* fca_w  = (const float*)d_in[5];
    const float* dconv_w= (const float*)d_in[6];
    const float* dconv_b= (const float*)d_in[7];
    float* out = (float*)d_out;

    unsigned char* ws = (unsigned char*)d_ws;
    unsigned short* xT = (unsigned short*)(ws);                 // 8 MB bf16 NHWC
    unsigned short* Bt = (unsigned short*)(ws + 8388608);       // 1.18 MB
    float* dwcT        = (float*)(ws + 9568256);                // 9 KB
    float* OX          = (float*)(ws + 9577472);                // 64 KB
    float* OY          = (float*)(ws + 9643008);                // 64 KB

    k_transpose<<<1024, 256, 0, stream>>>(x, xT);
    k_packB<<<2304, 256, 0, stream>>>(dconv_w, Bt, dwc_w, dwcT);
    k_offsets<<<512, 512, 0, stream>>>(xT, dwcT, ln_w, ln_b, fcd_w, fca_w, OX, OY);
    k_main<<<512, 512, 0, stream>>>(xT, OX, OY, Bt, dconv_b, out);
}

// Round 12
// 73.491 us; speedup vs baseline: 2.5812x; 1.0395x over previous
//
#include <hip/hip_runtime.h>
#include <hip/hip_bf16.h>

#define B_   4
#define C_   256
#define CO_  256
#define H_   64
#define W_   64
#define HW_  4096

typedef __attribute__((ext_vector_type(8))) short short8;
typedef __attribute__((ext_vector_type(4))) float f32x4;
typedef __attribute__((ext_vector_type(2))) float f32x2;

static __device__ __forceinline__ unsigned short f2bf(float f) {
    unsigned u = __builtin_bit_cast(unsigned, f);
    unsigned r = (u + 0x7fffu + ((u >> 16) & 1u)) >> 16;
    return (unsigned short)r;
}
static __device__ __forceinline__ f32x2 pk_mul(f32x2 a, f32x2 b) {
    f32x2 d; asm("v_pk_mul_f32 %0, %1, %2" : "=v"(d) : "v"(a), "v"(b)); return d;
}
static __device__ __forceinline__ f32x2 pk_fma(f32x2 a, f32x2 b, f32x2 c) {
    f32x2 d; asm("v_pk_fma_f32 %0, %1, %2, %3" : "=v"(d) : "v"(a), "v"(b), "v"(c)); return d;
}
static __device__ __forceinline__ f32x2 pk_add(f32x2 a, f32x2 b) {
    f32x2 d; asm("v_pk_add_f32 %0, %1, %2" : "=v"(d) : "v"(a), "v"(b)); return d;
}
static __device__ __forceinline__ unsigned cvtpk(float a, float b) {
    unsigned r; asm("v_cvt_pk_bf16_f32 %0, %1, %2" : "=v"(r) : "v"(a), "v"(b)); return r;
}
static __device__ __forceinline__ f32x2 unpack_bf2(unsigned d) {
    f32x2 v;
    v.x = __builtin_bit_cast(float, d << 16);
    v.y = __builtin_bit_cast(float, d & 0xffff0000u);
    return v;
}

// ---------------- K1: fused {NCHW->NHWC bf16 transpose} + {packB} + {dwcT} -----------
__global__ void k_pre(const float* __restrict__ x, unsigned short* __restrict__ xT,
                      const float* __restrict__ w, unsigned short* __restrict__ Bt,
                      const float* __restrict__ dwc_w, float* __restrict__ dwcT)
{
    int bid = blockIdx.x;
    int tid = threadIdx.x;
    if (bid < 1024) {
        // transpose: 1024 = b(4) * hwT(128) * cT(2)
        __shared__ float t[32][132];
        int b   = bid >> 8;
        int rem = bid & 255;
        int hwT = rem >> 1, cT = rem & 1;
        int hw0 = hwT * 32, c0 = cT * 128;
        const float* src = x + (size_t)b * C_ * HW_;
        {
            int hw4 = (tid & 7) << 2;
            int cr  = tid >> 3;
#pragma unroll
            for (int it = 0; it < 4; ++it) {
                int c = cr + it * 32;
                f32x4 v = *(const f32x4*)(src + (size_t)(c0 + c) * HW_ + hw0 + hw4);
                t[hw4 + 0][c] = v.x;
                t[hw4 + 1][c] = v.y;
                t[hw4 + 2][c] = v.z;
                t[hw4 + 3][c] = v.w;
            }
        }
        __syncthreads();
        {
            int c8  = (tid & 15) << 3;
            int hwr = tid >> 4;
            unsigned short* dst = xT + (size_t)(((b << 12) + hw0) * 256) + c0 + c8;
#pragma unroll
            for (int it = 0; it < 2; ++it) {
                int hw = hwr + it * 16;
                f32x4 va = *(const f32x4*)&t[hw][c8];
                f32x4 vb = *(const f32x4*)&t[hw][c8 + 4];
                uint4 u;
                u.x = cvtpk(va.x, va.y);
                u.y = cvtpk(va.z, va.w);
                u.z = cvtpk(vb.x, vb.y);
                u.w = cvtpk(vb.z, vb.w);
                *(uint4*)(dst + (size_t)hw * 256) = u;
            }
        }
    } else {
        // packB: Bt[((((k*16+og)*8+ks)*16+l15)*4+l4)*8+j] = w[(o*C+c)*9+k]
        int pb = bid - 1024;                   // 0..2303
        if (pb < 9) dwcT[pb * 256 + tid] = dwc_w[tid * 9 + pb];
        int e = pb * 256 + tid;
        int j   = e & 7;
        int l4  = (e >> 3) & 3;
        int l15 = (e >> 5) & 15;
        int ks  = (e >> 9) & 7;
        int og  = (e >> 12) & 15;
        int k   = e >> 16;
        int o = og * 16 + l15;
        int c = ks * 32 + l4 * 8 + j;
        Bt[e] = f2bf(w[(o * C_ + c) * 9 + k]);
    }
}

// ---------------- K2: offsets — 512 blocks x 512 thr, 16 lanes/position, no LDS ------
__global__ void k_offsets(const unsigned short* __restrict__ xT,
                          const float* __restrict__ dwcT,
                          const float* __restrict__ ln_w,
                          const float* __restrict__ ln_b,
                          const float* __restrict__ fcd_w,
                          const float* __restrict__ fca_w,
                          float* __restrict__ OX, float* __restrict__ OY)
{
    int tid = threadIdx.x;
    int bi = blockIdx.x;
    int g = ((bi & 7) << 6) | (bi >> 3);   // XCD swizzle
    int p0 = g << 5;
    int b = p0 >> 12;
    int y = (p0 >> 6) & 63;
    int xh = p0 & 63;
    int gpos = tid >> 4;                   // 0..31
    int csub = tid & 15;
    int ch0 = csub << 4;
    const unsigned short* xb = xT + (size_t)b * HW_ * C_;

    f32x2 acc2[8];
#pragma unroll
    for (int i = 0; i < 8; ++i) { acc2[i].x = 0.f; acc2[i].y = 0.f; }
#pragma unroll
    for (int j = 0; j < 9; ++j) {
        int gy = y + j / 3 - 1, gx = xh + gpos + j % 3 - 1;
        if (gy >= 0 && gy < H_ && gx >= 0 && gx < W_) {
            const unsigned short* p = xb + (size_t)((gy << 6) + gx) * 256 + ch0;
            short8 rlo = *(const short8*)(p);
            short8 rhi = *(const short8*)(p + 8);
            const float* wrow = dwcT + j * 256 + ch0;
#pragma unroll
            for (int q = 0; q < 4; ++q) {
                f32x4 wv = *(const f32x4*)(wrow + q * 4);
                f32x2 w01v; w01v.x = wv.x; w01v.y = wv.y;
                f32x2 w23v; w23v.x = wv.z; w23v.y = wv.w;
                unsigned lo = (q < 2) ? ((unsigned*)&rlo)[q * 2] : ((unsigned*)&rhi)[(q - 2) * 2];
                unsigned hi = (q < 2) ? ((unsigned*)&rlo)[q * 2 + 1] : ((unsigned*)&rhi)[(q - 2) * 2 + 1];
                acc2[q * 2 + 0] = pk_fma(unpack_bf2(lo), w01v, acc2[q * 2 + 0]);
                acc2[q * 2 + 1] = pk_fma(unpack_bf2(hi), w23v, acc2[q * 2 + 1]);
            }
        }
    }
    f32x2 sum2, sq2;
    sum2.x = 0.f; sum2.y = 0.f; sq2.x = 0.f; sq2.y = 0.f;
#pragma unroll
    for (int i = 0; i < 8; ++i) {
        sum2 = pk_add(sum2, acc2[i]);
        sq2  = pk_fma(acc2[i], acc2[i], sq2);
    }
    float s1 = sum2.x + sum2.y, s2 = sq2.x + sq2.y;
#pragma unroll
    for (int m = 1; m <= 8; m <<= 1) {
        s1 += __shfl_xor(s1, m);
        s2 += __shfl_xor(s2, m);
    }
    float mu  = s1 * (1.f / 256.f);
    float var = s2 * (1.f / 256.f) - mu * mu;
    float rs  = rsqrtf(var + 1e-5f);
    float d1 = 0.f, d2 = 0.f;
#pragma unroll
    for (int q = 0; q < 4; ++q) {
        f32x4 lwv = *(const f32x4*)(ln_w  + ch0 + q * 4);
        f32x4 lbv = *(const f32x4*)(ln_b  + ch0 + q * 4);
        f32x4 fdv = *(const f32x4*)(fcd_w + ch0 + q * 4);
        f32x4 fav = *(const f32x4*)(fca_w + ch0 + q * 4);
#pragma unroll
        for (int i = 0; i < 4; ++i) {
            float av = (i & 1) ? acc2[q * 2 + (i >> 1)].y : acc2[q * 2 + (i >> 1)].x;
            float hn = (av - mu) * rs * lwv[i] + lbv[i];
            hn = fmaxf(hn, 0.f);
            d1 = fmaf(hn, fdv[i], d1);
            d2 = fmaf(hn, fav[i], d2);
        }
    }
#pragma unroll
    for (int m = 1; m <= 8; m <<= 1) {
        d1 += __shfl_xor(d1, m);
        d2 += __shfl_xor(d2, m);
    }
    if (csub == 0) {
        float r0 = fmaxf(d1, 0.f);
        float theta = d2 / (1.f + fabsf(d2)) * 0.017453292519943295f;
        int pos = p0 + gpos;
        OX[pos] = r0 * cosf(theta);
        OY[pos] = r0 * sinf(theta);
    }
}

// ---------------- K3: implicit GEMM deformable conv, half-tap dbuf, 32KB LDS ---------
// 512 blocks x 512 threads. Block = full row (64 pos) x 128 outs (N half).
// K split in halves: h0 -> buf0, h1 -> buf1 (16KB each). 4 blocks/CU target.
// Epilogue: direct global stores (no LDS).
__launch_bounds__(512, 4)
__global__ void k_main(const unsigned short* __restrict__ xT,
                       const float* __restrict__ OX, const float* __restrict__ OY,
                       const unsigned short* __restrict__ Bt,
                       const float* __restrict__ bias,
                       float* __restrict__ out)
{
    __shared__ __align__(16) unsigned char smem[32768];   // 2 x 16KB half-tap buffers

    int tid = threadIdx.x;
    int bi = blockIdx.x;
    int g = ((bi & 7) << 6) | (bi >> 3);   // XCD-chunked; pair (2t,2t+1) = same row
    int tile = g >> 1;                     // 0..255 : (b, y) row
    int n0g = g & 1;                       // N half
    int b = tile >> 6;
    int y = tile & 63;

    int lane = tid & 63, wid = tid >> 6;
    int l15 = lane & 15, l4 = lane >> 4;

    f32x4 acc[4];
#pragma unroll
    for (int m = 0; m < 4; ++m) {
        acc[m].x = 0.f; acc[m].y = 0.f; acc[m].z = 0.f; acc[m].w = 0.f;
    }

    int gpos = tid >> 3;                   // 0..63 : position (x coordinate)
    unsigned csub = (unsigned)tid & 7u;
    const char* xbB = (const char*)(xT + (size_t)b * HW_ * C_);
    const unsigned short* bwave = Bt + (unsigned)(n0g * 8 + wid) * 4096u
                                     + (unsigned)(l15 * 32 + l4 * 8);
    unsigned rowb = (unsigned)gpos * 256u;
    unsigned wsl0 = (csub ^ ((unsigned)gpos & 15u)) << 4;        // cq2=0 slot byte
    unsigned wsl1 = ((8u + csub) ^ ((unsigned)gpos & 15u)) << 4; // cq2=1 slot byte
    float ox = OX[(tile << 6) + gpos], oy = OY[(tile << 6) + gpos];

    // persistent per-tap gather state
    unsigned o00, o01, o10, o11;
    f32x2 W00, W01, W10, W11;

#define GADDR(k)                                                                  \
    {   int ky = (k) / 3, kx = (k) - ky * 3;                                      \
        float dyv = ((k) <= 4) ? ox : oy;                                         \
        float dxv = ((k) <= 3) ? ox : oy;                                         \
        float py = (float)(y - 1 + ky) + dyv;                                     \
        float px = (float)(gpos - 1 + kx) + dxv;                                  \
        float y0f = floorf(py), x0f = floorf(px);                                 \
        int y0 = (int)y0f, x0 = (int)x0f;                                         \
        int y1 = y0 + 1, x1 = x0 + 1;                                             \
        float wy1 = py - y0f, wy0 = 1.f - wy1;                                    \
        float wx1 = px - x0f, wx0 = 1.f - wx1;                                    \
        float vy0 = (y0 >= 0 && y0 < H_) ? 1.f : 0.f;                             \
        float vy1 = (y1 >= 0 && y1 < H_) ? 1.f : 0.f;                             \
        float vx0 = (x0 >= 0 && x0 < W_) ? 1.f : 0.f;                             \
        float vx1 = (x1 >= 0 && x1 < W_) ? 1.f : 0.f;                             \
        float w00 = wy0 * wx0 * vy0 * vx0, w01 = wy0 * wx1 * vy0 * vx1;           \
        float w10 = wy1 * wx0 * vy1 * vx0, w11 = wy1 * wx1 * vy1 * vx1;           \
        W00.x = w00; W00.y = w00; W01.x = w01; W01.y = w01;                       \
        W10.x = w10; W10.y = w10; W11.x = w11; W11.y = w11;                       \
        int y0c = min(max(y0, 0), H_ - 1), y1c = min(max(y1, 0), H_ - 1);         \
        int x0c = min(max(x0, 0), W_ - 1), x1c = min(max(x1, 0), W_ - 1);         \
        unsigned cb = csub << 4;                                                  \
        o00 = (unsigned)((y0c << 6) + x0c) * 512u + cb;                           \
        o01 = (unsigned)((y0c << 6) + x1c) * 512u + cb;                           \
        o10 = (unsigned)((y1c << 6) + x0c) * 512u + cb;                           \
        o11 = (unsigned)((y1c << 6) + x1c) * 512u + cb;                           \
    }

    // gather channels [h*128, (h+1)*128) of this position into buffer hbase
#define GATHER_HALF(h, hbase)                                                     \
    {   _Pragma("unroll")                                                         \
        for (int cq2 = 0; cq2 < 2; ++cq2) {                                       \
            unsigned gb = (unsigned)(h) * 256u + (unsigned)cq2 * 128u;            \
            short8 r00 = *(const short8*)(xbB + o00 + gb);                        \
            short8 r01 = *(const short8*)(xbB + o01 + gb);                        \
            short8 r10 = *(const short8*)(xbB + o10 + gb);                        \
            short8 r11 = *(const short8*)(xbB + o11 + gb);                        \
            uint4 pkv;                                                            \
            _Pragma("unroll")                                                     \
            for (int dw = 0; dw < 4; ++dw) {                                      \
                f32x2 a2 = pk_mul(unpack_bf2(((unsigned*)&r00)[dw]), W00);        \
                a2 = pk_fma(unpack_bf2(((unsigned*)&r01)[dw]), W01, a2);          \
                a2 = pk_fma(unpack_bf2(((unsigned*)&r10)[dw]), W10, a2);          \
                a2 = pk_fma(unpack_bf2(((unsigned*)&r11)[dw]), W11, a2);          \
                ((unsigned*)&pkv)[dw] = cvtpk(a2.x, a2.y);                        \
            }                                                                     \
            *(uint4*)(smem + (hbase) + rowb + (cq2 ? wsl1 : wsl0)) = pkv;         \
        }                                                                         \
    }

    // MFMA on half h of tap k from buffer hbase
#define MFMA_HALF(k, h, hbase)                                                    \
    {   const unsigned short* bk = bwave + (unsigned)(k) * 65536u;                \
        _Pragma("unroll")                                                         \
        for (int ks2 = 0; ks2 < 4; ++ks2) {                                       \
            int ks = (h) * 4 + ks2;                                               \
            short8 bf = *(const short8*)(bk + ks * 512);                          \
            unsigned sl = ((unsigned)(ks2 * 4 + l4) ^ (unsigned)l15) << 4;        \
            _Pragma("unroll")                                                     \
            for (int mf = 0; mf < 4; ++mf) {                                      \
                unsigned row = (unsigned)(mf * 16 + l15);                         \
                short8 a = *(const short8*)(smem + (hbase) + row * 256u + sl);    \
                acc[mf] = __builtin_amdgcn_mfma_f32_16x16x32_bf16(a, bf, acc[mf], 0, 0, 0); \
            }                                                                     \
        }                                                                         \
    }

    // ---- prologue: tap 0 half 0 into buf0 ----
    GADDR(0);
    GATHER_HALF(0, 0u);
    __syncthreads();

#pragma unroll
    for (int k = 0; k < 9; ++k) {
        // phase A: MFMA(k, h0, buf0) || gather(k, h1 -> buf1)
        GATHER_HALF(1, 16384u);
        MFMA_HALF(k, 0, 0u);
        __syncthreads();
        // phase B: MFMA(k, h1, buf1) || gather(k+1, h0 -> buf0)
        if (k < 8) {
            GADDR(k + 1);
            GATHER_HALF(0, 0u);
        }
        MFMA_HALF(k, 1, 16384u);
        __syncthreads();
    }

    // ---- epilogue: direct global stores ----
    int col = n0g * 128 + wid * 16 + l15;
    float bv = bias[col];
    float* obase = out + ((size_t)(b * CO_ + col)) * HW_ + (y << 6);
#pragma unroll
    for (int mf = 0; mf < 4; ++mf) {
        f32x4 v;
        v.x = acc[mf].x + bv;
        v.y = acc[mf].y + bv;
        v.z = acc[mf].z + bv;
        v.w = acc[mf].w + bv;
        *(f32x4*)(obase + mf * 16 + l4 * 4) = v;
    }
}

extern "C" void kernel_launch(void* const* d_in, const int* in_sizes, int n_in,
                              void* d_out, int out_size, void* d_ws, size_t ws_size,
                              hipStream_t stream) {
    const float* x      = (const float*)d_in[0];
    const float* dwc_w  = (const float*)d_in[1];
    const float* ln_w   = (const float*)d_in[2];
    const float* ln_b   = (const float*)d_in[3];
    const float* fcd_w  = (const float*)d_in[4];
    const float* fca_w  = (const float*)d_in[5];
    const float* dconv_w= (const float*)d_in[6];
    const float* dconv_b= (const float*)d_in[7];
    float* out = (float*)d_out;

    unsigned char* ws = (unsigned char*)d_ws;
    unsigned short* xT = (unsigned short*)(ws);                 // 8 MB bf16 NHWC
    unsigned short* Bt = (unsigned short*)(ws + 8388608);       // 1.18 MB
    float* dwcT        = (float*)(ws + 9568256);                // 9 KB
    float* OX          = (float*)(ws + 9577472);                // 64 KB
    float* OY          = (float*)(ws + 9643008);                // 64 KB

    k_pre<<<3328, 256, 0, stream>>>(x, xT, dconv_w, Bt, dwc_w, dwcT);
    k_offsets<<<512, 512, 0, stream>>>(xT, dwcT, ln_w, ln_b, fcd_w, fca_w, OX, OY);
    k_main<<<512, 512, 0, stream>>>(xT, OX, OY, Bt, dconv_b, out);
}